// Round 1
// baseline (1276.110 us; speedup 1.0000x reference)
//
#include <hip/hip_runtime.h>

// Shapes
// B=8, NF=64, FIN=192, FH=128, FOUT=64, LAT=512, P_TOTAL=61824
// dyn param offsets: w_in 0, b_in 24576, w_mid 24704, b_mid 41088,
//                    w_out 41216, b_out 49408, w_sk 49472, b_sk 61760

#define BATCH 8
#define PT 61824

__device__ __forceinline__ float lrelu(float v) { return v > 0.f ? v : 0.2f * v; }

// ---------------------------------------------------------------------------
// Kernel 1: hypernetwork  dyn[b][p] = sum_k inj[b][k] * hyp_w[k][p] + hyp_b[p]
// ---------------------------------------------------------------------------
__global__ __launch_bounds__(256) void hyper_kernel(
    const float* __restrict__ inj, const float* __restrict__ hw,
    const float* __restrict__ hb, float* __restrict__ dyn)
{
    __shared__ float s_l[512 * 8];  // transposed: s_l[k*8 + b]
    int t = threadIdx.x;
    for (int i = t; i < 4096; i += 256) {
        int b = i >> 9, k = i & 511;
        s_l[k * 8 + b] = inj[i];
    }
    __syncthreads();
    int p = blockIdx.x * 256 + t;
    if (p >= PT) return;
    float acc[8];
#pragma unroll
    for (int b = 0; b < 8; ++b) acc[b] = 0.f;
    for (int k = 0; k < 512; ++k) {
        float w = hw[(size_t)k * PT + p];
        float4 a0 = *(const float4*)&s_l[k * 8];
        float4 a1 = *(const float4*)&s_l[k * 8 + 4];
        acc[0] += a0.x * w; acc[1] += a0.y * w; acc[2] += a0.z * w; acc[3] += a0.w * w;
        acc[4] += a1.x * w; acc[5] += a1.y * w; acc[6] += a1.z * w; acc[7] += a1.w * w;
    }
    float bias = hb[p];
#pragma unroll
    for (int b = 0; b < 8; ++b) dyn[(size_t)b * PT + p] = acc[b] + bias;
}

// ---------------------------------------------------------------------------
// Kernel 2: stem = conv1x1(x, in_w, in_b) then res_block(inrb) -> emb0
// block = (sample, 64-pixel tile), 256 threads
// ---------------------------------------------------------------------------
__global__ __launch_bounds__(256) void stem_kernel(
    const float* __restrict__ x, const float* __restrict__ in_w,
    const float* __restrict__ in_b,
    const float* __restrict__ w0, const float* __restrict__ b0,
    const float* __restrict__ w1, const float* __restrict__ b1,
    float* __restrict__ out0)
{
    const int HW = 128 * 128;
    __shared__ float s_t0[64 * 68];
    __shared__ float s_v[64 * 68];
    const int tilesPer = HW / 64;  // 256
    const int b = blockIdx.x / tilesPer;
    const int tile = blockIdx.x - b * tilesPer;
    const int pix0 = tile * 64;
    const int t = threadIdx.x;

    // phase 1: t0 = in_w * x + in_b ; also store act(t0)
    for (int job = t; job < 64 * 64; job += 256) {
        int p = job & 63, c = job >> 6;
        const float* xb = x + (size_t)b * 3 * HW + pix0 + p;
        float v = in_b[c] + xb[0] * in_w[c * 3] + xb[HW] * in_w[c * 3 + 1]
                + xb[2 * HW] * in_w[c * 3 + 2];
        s_t0[p * 68 + c] = v;
        s_v[p * 68 + c] = lrelu(v);
    }
    __syncthreads();

    const int o = t & 63, g = t >> 6;  // 4 groups x 16 pixels
    // phase 2: z = w0 * act(t0) + b0 ; v = act(z)
    {
        float acc[16];
#pragma unroll
        for (int p = 0; p < 16; ++p) acc[p] = 0.f;
        const float* wr = w0 + o * 64;
        for (int k4 = 0; k4 < 16; ++k4) {
            float4 wv = ((const float4*)wr)[k4];
#pragma unroll
            for (int p = 0; p < 16; ++p) {
                float4 uv = *(const float4*)&s_v[(g * 16 + p) * 68 + k4 * 4];
                acc[p] += wv.x * uv.x + wv.y * uv.y + wv.z * uv.z + wv.w * uv.w;
            }
        }
        __syncthreads();  // all reads of s_v done before overwrite
        float bi = b0[o];
#pragma unroll
        for (int p = 0; p < 16; ++p) s_v[(g * 16 + p) * 68 + o] = lrelu(acc[p] + bi);
    }
    __syncthreads();
    // phase 3: r = t0 + 0.1*(w1 * v + b1)
    {
        float acc[16];
#pragma unroll
        for (int p = 0; p < 16; ++p) acc[p] = 0.f;
        const float* wr = w1 + o * 64;
        for (int k4 = 0; k4 < 16; ++k4) {
            float4 wv = ((const float4*)wr)[k4];
#pragma unroll
            for (int p = 0; p < 16; ++p) {
                float4 uv = *(const float4*)&s_v[(g * 16 + p) * 68 + k4 * 4];
                acc[p] += wv.x * uv.x + wv.y * uv.y + wv.z * uv.z + wv.w * uv.w;
            }
        }
        float bi = b1[o];
        float* ob = out0 + ((size_t)b * 64 + o) * HW;
#pragma unroll
        for (int p = 0; p < 16; ++p) {
            int pix = pix0 + g * 16 + p;
            ob[pix] = s_t0[(g * 16 + p) * 68 + o] + 0.1f * (acc[p] + bi);
        }
    }
}

// ---------------------------------------------------------------------------
// Kernel 3: fused iteration: y = out + leak * dyna_residual(sin_sobel(out))
// block = (sample, 32-pixel tile), 256 threads
// ---------------------------------------------------------------------------
#define TILE 32

__global__ __launch_bounds__(256) void iter_kernel(
    const float* __restrict__ cur, const float* __restrict__ dyn,
    const float* __restrict__ leak_p, float* __restrict__ y, int S)
{
    __shared__ float s_s[TILE * 196];   // sin_sobel features [pix][192]
    __shared__ float s_h1[TILE * 132];  // act(h1) [pix][128]
    __shared__ float s_h2[TILE * 132];  // act(h2) [pix][128]
    const int HW = S * S;
    const int tilesPer = (HW + TILE - 1) / TILE;
    const int b = blockIdx.x / tilesPer;
    const int tile = blockIdx.x - b * tilesPer;
    const int pix0 = tile * TILE;
    const int t = threadIdx.x;
    const float* base = cur + (size_t)b * 64 * HW;

    // phase 1: sin_sobel into LDS (identity | sobel-x | sobel-y), zero-pad 1
    for (int job = t; job < TILE * 64; job += 256) {
        int p = job & (TILE - 1);
        int c = job >> 5;
        int gpx = pix0 + p;
        float id = 0.f, sx = 0.f, sy = 0.f;
        if (gpx < HW) {
            int yy = gpx / S, xx = gpx - yy * S;
            const float* ch = base + (size_t)c * HW;
            float v[3][3];
#pragma unroll
            for (int dy = 0; dy < 3; ++dy)
#pragma unroll
                for (int dx = 0; dx < 3; ++dx) {
                    int ay = yy + dy - 1, ax = xx + dx - 1;
                    v[dy][dx] = (ay >= 0 && ay < S && ax >= 0 && ax < S) ? ch[ay * S + ax] : 0.f;
                }
            id = v[1][1];
            sx = (v[0][0] - v[0][2] + 2.f * (v[1][0] - v[1][2]) + v[2][0] - v[2][2]) * 0.125f;
            sy = (v[0][0] + 2.f * v[0][1] + v[0][2] - v[2][0] - 2.f * v[2][1] - v[2][2]) * 0.125f;
        }
        s_s[p * 196 + c] = id;
        s_s[p * 196 + 64 + c] = sx;
        s_s[p * 196 + 128 + c] = sy;
    }
    __syncthreads();

    const float* pb = dyn + (size_t)b * PT;

    // phase 2: h1 = act(w_in * s + b_in)  [128 out, K=192]
    {
        int o = t & 127, g = t >> 7;
        float acc[16];
#pragma unroll
        for (int p = 0; p < 16; ++p) acc[p] = 0.f;
        const float* wr = pb + o * 192;
        for (int k4 = 0; k4 < 48; ++k4) {
            float4 wv = ((const float4*)wr)[k4];
#pragma unroll
            for (int p = 0; p < 16; ++p) {
                float4 sv = *(const float4*)&s_s[(g * 16 + p) * 196 + k4 * 4];
                acc[p] += wv.x * sv.x + wv.y * sv.y + wv.z * sv.z + wv.w * sv.w;
            }
        }
        float bi = pb[24576 + o];
#pragma unroll
        for (int p = 0; p < 16; ++p) s_h1[(g * 16 + p) * 132 + o] = lrelu(acc[p] + bi);
    }
    __syncthreads();

    // phase 3: h2 = act(w_mid * h1 + b_mid)  [128 out, K=128]
    {
        int o = t & 127, g = t >> 7;
        float acc[16];
#pragma unroll
        for (int p = 0; p < 16; ++p) acc[p] = 0.f;
        const float* wr = pb + 24704 + o * 128;
        for (int k4 = 0; k4 < 32; ++k4) {
            float4 wv = ((const float4*)wr)[k4];
#pragma unroll
            for (int p = 0; p < 16; ++p) {
                float4 hv = *(const float4*)&s_h1[(g * 16 + p) * 132 + k4 * 4];
                acc[p] += wv.x * hv.x + wv.y * hv.y + wv.z * hv.z + wv.w * hv.w;
            }
        }
        float bi = pb[41088 + o];
#pragma unroll
        for (int p = 0; p < 16; ++p) s_h2[(g * 16 + p) * 132 + o] = lrelu(acc[p] + bi);
    }
    __syncthreads();

    // phase 4: d = w_out*h2 + b_out + w_sk*s + b_sk ; y = out + leak*d
    {
        int o = t & 63, g = t >> 6;  // 4 groups x 8 pixels
        float acc[8];
#pragma unroll
        for (int p = 0; p < 8; ++p) acc[p] = 0.f;
        const float* wo = pb + 41216 + o * 128;
        for (int k4 = 0; k4 < 32; ++k4) {
            float4 wv = ((const float4*)wo)[k4];
#pragma unroll
            for (int p = 0; p < 8; ++p) {
                float4 hv = *(const float4*)&s_h2[(g * 8 + p) * 132 + k4 * 4];
                acc[p] += wv.x * hv.x + wv.y * hv.y + wv.z * hv.z + wv.w * hv.w;
            }
        }
        const float* wk = pb + 49472 + o * 192;
        for (int k4 = 0; k4 < 48; ++k4) {
            float4 wv = ((const float4*)wk)[k4];
#pragma unroll
            for (int p = 0; p < 8; ++p) {
                float4 sv = *(const float4*)&s_s[(g * 8 + p) * 196 + k4 * 4];
                acc[p] += wv.x * sv.x + wv.y * sv.y + wv.z * sv.z + wv.w * sv.w;
            }
        }
        float lk = fminf(fmaxf(leak_p[0], 0.001f), 1000.f);
        float bi = pb[49408 + o] + pb[61760 + o];  // b_out + b_sk
        float* yb = y + ((size_t)b * 64 + o) * HW;
#pragma unroll
        for (int p = 0; p < 8; ++p) {
            int gpx = pix0 + g * 8 + p;
            if (gpx < HW) yb[gpx] = s_s[(g * 8 + p) * 196 + o] + lk * (acc[p] + bi);
        }
    }
}

// ---------------------------------------------------------------------------
// Kernel 4: downsample = gauss3x3 (zero-pad) then 2x2 mean
// ---------------------------------------------------------------------------
__global__ __launch_bounds__(256) void down_kernel(
    const float* __restrict__ yin, float* __restrict__ outp, int S, int total)
{
    int idx = blockIdx.x * 256 + threadIdx.x;
    if (idx >= total) return;
    const float ga = 0.60653065971263342f;
    const float gs = 1.f / ((1.f + 2.f * ga) * (1.f + 2.f * ga));
    float g1[3] = {ga, 1.f, ga};
    int S2 = S >> 1;
    int ox = idx % S2;
    int r = idx / S2;
    int oy = r % S2;
    int bc = r / S2;  // [0, B*64)
    const float* src = yin + (size_t)bc * S * S;
    float acc = 0.f;
#pragma unroll
    for (int py = 0; py < 2; ++py)
#pragma unroll
        for (int px = 0; px < 2; ++px) {
            int cy = 2 * oy + py, cx = 2 * ox + px;
#pragma unroll
            for (int dy = 0; dy < 3; ++dy) {
                int ay = cy + dy - 1;
                if (ay < 0 || ay >= S) continue;
#pragma unroll
                for (int dx = 0; dx < 3; ++dx) {
                    int ax = cx + dx - 1;
                    if (ax < 0 || ax >= S) continue;
                    acc += g1[dy] * g1[dx] * src[ay * S + ax];
                }
            }
        }
    outp[idx] = acc * 0.25f * gs;
}

// ---------------------------------------------------------------------------
// Kernel 5: head = res_block(outrb) -> spatial mean -> lin_res x2 -> lat
// one block per sample
// ---------------------------------------------------------------------------
__global__ __launch_bounds__(256) void head_kernel(
    const float* __restrict__ emb6,
    const float* __restrict__ w0, const float* __restrict__ b0,
    const float* __restrict__ w1, const float* __restrict__ b1,
    const float* __restrict__ l1_sw, const float* __restrict__ l1_sb,
    const float* __restrict__ l1_w1, const float* __restrict__ l1_b1,
    const float* __restrict__ l1_w2, const float* __restrict__ l1_b2,
    const float* __restrict__ l2_w1, const float* __restrict__ l2_b1,
    const float* __restrict__ l2_w2, const float* __restrict__ l2_b2,
    const float* __restrict__ lo_w, const float* __restrict__ lo_b,
    float* __restrict__ lat)
{
    __shared__ float sm_t[256], sm_v[256], sm_r[256];
    __shared__ float sm_h[64];
    __shared__ float sm_u1[1024];
    __shared__ float sm_h1[512], sm_t3[512], sm_h2[512];
    int b = blockIdx.x, t = threadIdx.x;

    sm_t[t] = emb6[b * 256 + t];  // [c*4 + p]
    __syncthreads();
    {
        int o = t & 63, p = t >> 6;
        float acc = 0.f;
        for (int k = 0; k < 64; ++k) acc += w0[o * 64 + k] * lrelu(sm_t[k * 4 + p]);
        sm_v[o * 4 + p] = lrelu(acc + b0[o]);
    }
    __syncthreads();
    {
        int o = t & 63, p = t >> 6;
        float acc = 0.f;
        for (int k = 0; k < 64; ++k) acc += w1[o * 64 + k] * sm_v[k * 4 + p];
        sm_r[o * 4 + p] = sm_t[o * 4 + p] + 0.1f * (acc + b1[o]);
    }
    __syncthreads();
    if (t < 64)
        sm_h[t] = 0.25f * (sm_r[t * 4] + sm_r[t * 4 + 1] + sm_r[t * 4 + 2] + sm_r[t * 4 + 3]);
    __syncthreads();

    // lin_res 1: t1 = act(act(h) @ l1_w1 + b1)  [1024]
    {
        float acc[4] = {0.f, 0.f, 0.f, 0.f};
        for (int k = 0; k < 64; ++k) {
            float u = lrelu(sm_h[k]);
            const float* r = l1_w1 + k * 1024;
            acc[0] += u * r[t]; acc[1] += u * r[t + 256];
            acc[2] += u * r[t + 512]; acc[3] += u * r[t + 768];
        }
#pragma unroll
        for (int j = 0; j < 4; ++j)
            sm_u1[t + j * 256] = lrelu(acc[j] + l1_b1[t + j * 256]);
    }
    __syncthreads();
    // h1 = (h @ l1_sw + l1_sb) + 0.1*(t1 @ l1_w2 + l1_b2)  [512]
    {
        float acc[2] = {0.f, 0.f};
        for (int k = 0; k < 1024; ++k) {
            float u = sm_u1[k];
            acc[0] += u * l1_w2[k * 512 + t];
            acc[1] += u * l1_w2[k * 512 + t + 256];
        }
        float hs[2] = {0.f, 0.f};
        for (int k = 0; k < 64; ++k) {
            float h = sm_h[k];
            hs[0] += h * l1_sw[k * 512 + t];
            hs[1] += h * l1_sw[k * 512 + t + 256];
        }
        sm_h1[t] = hs[0] + l1_sb[t] + 0.1f * (acc[0] + l1_b2[t]);
        sm_h1[t + 256] = hs[1] + l1_sb[t + 256] + 0.1f * (acc[1] + l1_b2[t + 256]);
    }
    __syncthreads();
    // lin_res 2: t3 = act(act(h1) @ l2_w1 + b1)
    {
        float acc[2] = {0.f, 0.f};
        for (int k = 0; k < 512; ++k) {
            float u = lrelu(sm_h1[k]);
            acc[0] += u * l2_w1[k * 512 + t];
            acc[1] += u * l2_w1[k * 512 + t + 256];
        }
        sm_t3[t] = lrelu(acc[0] + l2_b1[t]);
        sm_t3[t + 256] = lrelu(acc[1] + l2_b1[t + 256]);
    }
    __syncthreads();
    // h2 = h1 + 0.1*(t3 @ l2_w2 + b2)
    {
        float acc[2] = {0.f, 0.f};
        for (int k = 0; k < 512; ++k) {
            float u = sm_t3[k];
            acc[0] += u * l2_w2[k * 512 + t];
            acc[1] += u * l2_w2[k * 512 + t + 256];
        }
        sm_h2[t] = sm_h1[t] + 0.1f * (acc[0] + l2_b2[t]);
        sm_h2[t + 256] = sm_h1[t + 256] + 0.1f * (acc[1] + l2_b2[t + 256]);
    }
    __syncthreads();
    // lat = h2 @ lo_w + lo_b
    {
        float acc[2] = {0.f, 0.f};
        for (int k = 0; k < 512; ++k) {
            float u = sm_h2[k];
            acc[0] += u * lo_w[k * 512 + t];
            acc[1] += u * lo_w[k * 512 + t + 256];
        }
        lat[b * 512 + t] = acc[0] + lo_b[t];
        lat[b * 512 + t + 256] = acc[1] + lo_b[t + 256];
    }
}

// ---------------------------------------------------------------------------
extern "C" void kernel_launch(void* const* d_in, const int* in_sizes, int n_in,
                              void* d_out, int out_size, void* d_ws, size_t ws_size,
                              hipStream_t stream) {
    const float* x      = (const float*)d_in[0];
    const float* inj    = (const float*)d_in[1];
    const float* leak   = (const float*)d_in[2];
    const float* in_w   = (const float*)d_in[3];
    const float* in_b   = (const float*)d_in[4];
    const float* inrb_w0 = (const float*)d_in[5];
    const float* inrb_b0 = (const float*)d_in[6];
    const float* inrb_w1 = (const float*)d_in[7];
    const float* inrb_b1 = (const float*)d_in[8];
    const float* hyp_w  = (const float*)d_in[9];
    const float* hyp_b  = (const float*)d_in[10];
    const float* outrb_w0 = (const float*)d_in[11];
    const float* outrb_b0 = (const float*)d_in[12];
    const float* outrb_w1 = (const float*)d_in[13];
    const float* outrb_b1 = (const float*)d_in[14];
    const float* l1_sw  = (const float*)d_in[15];
    const float* l1_sb  = (const float*)d_in[16];
    const float* l1_w1  = (const float*)d_in[17];
    const float* l1_b1  = (const float*)d_in[18];
    const float* l1_w2  = (const float*)d_in[19];
    const float* l1_b2  = (const float*)d_in[20];
    const float* l2_w1  = (const float*)d_in[21];
    const float* l2_b1  = (const float*)d_in[22];
    const float* l2_w2  = (const float*)d_in[23];
    const float* l2_b2  = (const float*)d_in[24];
    const float* lo_w   = (const float*)d_in[25];
    const float* lo_b   = (const float*)d_in[26];

    float* out = (float*)d_out;
    float* dyn = (float*)d_ws;                  // 8*61824 floats
    float* ybuf = dyn + (size_t)BATCH * PT;     // 8*64*128*128 floats

    // 1. hypernetwork params
    hyper_kernel<<<(PT + 255) / 256, 256, 0, stream>>>(inj, hyp_w, hyp_b, dyn);

    // 2. stem -> emb0 (at out + 4096)
    size_t cur = 4096;
    stem_kernel<<<BATCH * 256, 256, 0, stream>>>(
        x, in_w, in_b, inrb_w0, inrb_b0, inrb_w1, inrb_b1, out + cur);

    // 3. six fused iterations, each: iter (full res) + downsample
    int S = 128;
    for (int i = 0; i < 6; ++i) {
        int tiles = (S * S + TILE - 1) / TILE;
        iter_kernel<<<BATCH * tiles, 256, 0, stream>>>(out + cur, dyn, leak, ybuf, S);
        int S2 = S >> 1;
        int total = BATCH * 64 * S2 * S2;
        size_t nxt = cur + (size_t)BATCH * 64 * S * S;
        down_kernel<<<(total + 255) / 256, 256, 0, stream>>>(ybuf, out + nxt, S, total);
        cur = nxt;
        S = S2;
    }

    // 4. head -> lat at out[0..4095]
    head_kernel<<<BATCH, 256, 0, stream>>>(
        out + cur, outrb_w0, outrb_b0, outrb_w1, outrb_b1,
        l1_sw, l1_sb, l1_w1, l1_b1, l1_w2, l1_b2,
        l2_w1, l2_b1, l2_w2, l2_b2, lo_w, lo_b, out);
}

// Round 2
// 783.181 us; speedup vs baseline: 1.6294x; 1.6294x over previous
//
#include <hip/hip_runtime.h>

// Shapes
// B=8, NF=64, FIN=192, FH=128, FOUT=64, LAT=512, P_TOTAL=61824
// dyn param offsets: w_in 0, b_in 24576, w_mid 24704, b_mid 41088,
//                    w_out 41216, b_out 49408, w_sk 49472, b_sk 61760

#define BATCH 8
#define PT 61824

typedef __attribute__((ext_vector_type(8))) short bf16x8;
typedef __attribute__((ext_vector_type(4))) float f32x4;

__device__ __forceinline__ float lrelu(float v) { return v > 0.f ? v : 0.2f * v; }

__device__ __forceinline__ short f2bf(float f) {
    union { float fv; unsigned u; } v; v.fv = f;
    return (short)((v.u + 0x7fffu + ((v.u >> 16) & 1u)) >> 16);  // RNE
}

// ---------------------------------------------------------------------------
// Kernel 1: hypernetwork  dyn[b][p] = sum_k inj[b][k] * hyp_w[k][p] + hyp_b[p]
// also emits bf16 copy for the MFMA iter kernel
// ---------------------------------------------------------------------------
__global__ __launch_bounds__(256) void hyper_kernel(
    const float* __restrict__ inj, const float* __restrict__ hw,
    const float* __restrict__ hb, float* __restrict__ dyn,
    short* __restrict__ dyn16)
{
    __shared__ float s_l[512 * 8];  // transposed: s_l[k*8 + b]
    int t = threadIdx.x;
    for (int i = t; i < 4096; i += 256) {
        int b = i >> 9, k = i & 511;
        s_l[k * 8 + b] = inj[i];
    }
    __syncthreads();
    int p = blockIdx.x * 256 + t;
    if (p >= PT) return;
    float acc[8];
#pragma unroll
    for (int b = 0; b < 8; ++b) acc[b] = 0.f;
    for (int k = 0; k < 512; ++k) {
        float w = hw[(size_t)k * PT + p];
        float4 a0 = *(const float4*)&s_l[k * 8];
        float4 a1 = *(const float4*)&s_l[k * 8 + 4];
        acc[0] += a0.x * w; acc[1] += a0.y * w; acc[2] += a0.z * w; acc[3] += a0.w * w;
        acc[4] += a1.x * w; acc[5] += a1.y * w; acc[6] += a1.z * w; acc[7] += a1.w * w;
    }
    float bias = hb[p];
#pragma unroll
    for (int b = 0; b < 8; ++b) {
        float v = acc[b] + bias;
        dyn[(size_t)b * PT + p] = v;
        dyn16[(size_t)b * PT + p] = f2bf(v);
    }
}

// ---------------------------------------------------------------------------
// Kernel 2: stem = conv1x1(x, in_w, in_b) then res_block(inrb) -> emb0
// ---------------------------------------------------------------------------
__global__ __launch_bounds__(256) void stem_kernel(
    const float* __restrict__ x, const float* __restrict__ in_w,
    const float* __restrict__ in_b,
    const float* __restrict__ w0, const float* __restrict__ b0,
    const float* __restrict__ w1, const float* __restrict__ b1,
    float* __restrict__ out0)
{
    const int HW = 128 * 128;
    __shared__ float s_t0[64 * 68];
    __shared__ float s_v[64 * 68];
    const int tilesPer = HW / 64;  // 256
    const int b = blockIdx.x / tilesPer;
    const int tile = blockIdx.x - b * tilesPer;
    const int pix0 = tile * 64;
    const int t = threadIdx.x;

    for (int job = t; job < 64 * 64; job += 256) {
        int p = job & 63, c = job >> 6;
        const float* xb = x + (size_t)b * 3 * HW + pix0 + p;
        float v = in_b[c] + xb[0] * in_w[c * 3] + xb[HW] * in_w[c * 3 + 1]
                + xb[2 * HW] * in_w[c * 3 + 2];
        s_t0[p * 68 + c] = v;
        s_v[p * 68 + c] = lrelu(v);
    }
    __syncthreads();

    const int o = t & 63, g = t >> 6;
    {
        float acc[16];
#pragma unroll
        for (int p = 0; p < 16; ++p) acc[p] = 0.f;
        const float* wr = w0 + o * 64;
        for (int k4 = 0; k4 < 16; ++k4) {
            float4 wv = ((const float4*)wr)[k4];
#pragma unroll
            for (int p = 0; p < 16; ++p) {
                float4 uv = *(const float4*)&s_v[(g * 16 + p) * 68 + k4 * 4];
                acc[p] += wv.x * uv.x + wv.y * uv.y + wv.z * uv.z + wv.w * uv.w;
            }
        }
        __syncthreads();
        float bi = b0[o];
#pragma unroll
        for (int p = 0; p < 16; ++p) s_v[(g * 16 + p) * 68 + o] = lrelu(acc[p] + bi);
    }
    __syncthreads();
    {
        float acc[16];
#pragma unroll
        for (int p = 0; p < 16; ++p) acc[p] = 0.f;
        const float* wr = w1 + o * 64;
        for (int k4 = 0; k4 < 16; ++k4) {
            float4 wv = ((const float4*)wr)[k4];
#pragma unroll
            for (int p = 0; p < 16; ++p) {
                float4 uv = *(const float4*)&s_v[(g * 16 + p) * 68 + k4 * 4];
                acc[p] += wv.x * uv.x + wv.y * uv.y + wv.z * uv.z + wv.w * uv.w;
            }
        }
        float bi = b1[o];
        float* ob = out0 + ((size_t)b * 64 + o) * HW;
#pragma unroll
        for (int p = 0; p < 16; ++p) {
            int pix = pix0 + g * 16 + p;
            ob[pix] = s_t0[(g * 16 + p) * 68 + o] + 0.1f * (acc[p] + bi);
        }
    }
}

// ---------------------------------------------------------------------------
// Kernel 3: fused iteration via MFMA: y = cur + leak * dyna_residual(sin_sobel(cur))
// block = (sample, 64-pixel tile), 256 threads = 4 waves
// waves partition output channels; each block reads the weight set once/layer
// ---------------------------------------------------------------------------
__global__ __launch_bounds__(256) void iter_kernel(
    const float* __restrict__ cur, const float* __restrict__ dynf,
    const short* __restrict__ dynb, const float* __restrict__ leak_p,
    float* __restrict__ y, int S, int sh)
{
    __shared__ short s_s[64 * 200];   // bf16 sobel features [pix][k], stride 200
    __shared__ short s_h1[64 * 136];  // bf16 act(h1) [pix][o]
    __shared__ short s_h2[64 * 136];  // bf16 act(h2) [pix][o]
    float* s_y = (float*)s_h1;        // fp32 out [o][pix], stride 68 (17408 B fits)

    const int HW = S * S;
    const int tilesPer = (HW + 63) >> 6;
    const int b = blockIdx.x / tilesPer;
    const int tile = blockIdx.x - b * tilesPer;
    const int pix0 = tile * 64;
    const int t = threadIdx.x;
    const float* base = cur + (size_t)b * 64 * HW;

    // phase 0: sin_sobel (identity | sobel-x | sobel-y) -> bf16 LDS, zero-pad 1
    for (int job = t; job < 4096; job += 256) {
        int p = job & 63, c = job >> 6;
        int gpx = pix0 + p;
        float id = 0.f, sx = 0.f, sy = 0.f;
        if (gpx < HW) {
            int yy = gpx >> sh, xx = gpx & (S - 1);
            const float* ch = base + (size_t)c * HW;
            float v[3][3];
#pragma unroll
            for (int dy = 0; dy < 3; ++dy)
#pragma unroll
                for (int dx = 0; dx < 3; ++dx) {
                    int ay = yy + dy - 1, ax = xx + dx - 1;
                    v[dy][dx] = (ay >= 0 && ay < S && ax >= 0 && ax < S) ? ch[ay * S + ax] : 0.f;
                }
            id = v[1][1];
            sx = (v[0][0] - v[0][2] + 2.f * (v[1][0] - v[1][2]) + v[2][0] - v[2][2]) * 0.125f;
            sy = (v[0][0] + 2.f * v[0][1] + v[0][2] - v[2][0] - 2.f * v[2][1] - v[2][2]) * 0.125f;
        }
        s_s[p * 200 + c] = f2bf(id);
        s_s[p * 200 + 64 + c] = f2bf(sx);
        s_s[p * 200 + 128 + c] = f2bf(sy);
    }
    __syncthreads();

    const int lane = t & 63, wv = t >> 6;
    const int lo = lane & 15, quad = lane >> 4;
    const short* wb = dynb + (size_t)b * PT;
    const float* pf = dynf + (size_t)b * PT;
    const f32x4 z4 = {0.f, 0.f, 0.f, 0.f};

    // phase 1: h1 = act(w_in * s + b_in)   O=128 (8 ntiles, 2/wave), K=192
    {
        f32x4 acc[2][4];
#pragma unroll
        for (int n = 0; n < 2; ++n)
#pragma unroll
            for (int mt = 0; mt < 4; ++mt) acc[n][mt] = z4;
        for (int k = 0; k < 6; ++k) {
            bf16x8 a[4];
#pragma unroll
            for (int mt = 0; mt < 4; ++mt)
                a[mt] = *(const bf16x8*)&s_s[(mt * 16 + lo) * 200 + k * 32 + quad * 8];
#pragma unroll
            for (int n = 0; n < 2; ++n) {
                int o = (wv * 2 + n) * 16 + lo;
                bf16x8 bb = *(const bf16x8*)&wb[o * 192 + k * 32 + quad * 8];
#pragma unroll
                for (int mt = 0; mt < 4; ++mt)
                    acc[n][mt] = __builtin_amdgcn_mfma_f32_16x16x32_bf16(a[mt], bb, acc[n][mt], 0, 0, 0);
            }
        }
#pragma unroll
        for (int n = 0; n < 2; ++n) {
            int o = (wv * 2 + n) * 16 + lo;
            float bi = pf[24576 + o];
#pragma unroll
            for (int mt = 0; mt < 4; ++mt)
#pragma unroll
                for (int r = 0; r < 4; ++r)
                    s_h1[(mt * 16 + quad * 4 + r) * 136 + o] = f2bf(lrelu(acc[n][mt][r] + bi));
        }
    }
    __syncthreads();

    // phase 2: h2 = act(w_mid * h1 + b_mid)   O=128, K=128
    {
        f32x4 acc[2][4];
#pragma unroll
        for (int n = 0; n < 2; ++n)
#pragma unroll
            for (int mt = 0; mt < 4; ++mt) acc[n][mt] = z4;
        for (int k = 0; k < 4; ++k) {
            bf16x8 a[4];
#pragma unroll
            for (int mt = 0; mt < 4; ++mt)
                a[mt] = *(const bf16x8*)&s_h1[(mt * 16 + lo) * 136 + k * 32 + quad * 8];
#pragma unroll
            for (int n = 0; n < 2; ++n) {
                int o = (wv * 2 + n) * 16 + lo;
                bf16x8 bb = *(const bf16x8*)&wb[24704 + o * 128 + k * 32 + quad * 8];
#pragma unroll
                for (int mt = 0; mt < 4; ++mt)
                    acc[n][mt] = __builtin_amdgcn_mfma_f32_16x16x32_bf16(a[mt], bb, acc[n][mt], 0, 0, 0);
            }
        }
        __syncthreads();  // all s_h1 reads done before s_y (aliased) writes later
#pragma unroll
        for (int n = 0; n < 2; ++n) {
            int o = (wv * 2 + n) * 16 + lo;
            float bi = pf[41088 + o];
#pragma unroll
            for (int mt = 0; mt < 4; ++mt)
#pragma unroll
                for (int r = 0; r < 4; ++r)
                    s_h2[(mt * 16 + quad * 4 + r) * 136 + o] = f2bf(lrelu(acc[n][mt][r] + bi));
        }
    }
    __syncthreads();

    // phase 3: d = w_out*h2 + w_sk*s + (b_out + b_sk)   O=64 (1 ntile/wave)
    {
        f32x4 acc[4];
#pragma unroll
        for (int mt = 0; mt < 4; ++mt) acc[mt] = z4;
        int o = wv * 16 + lo;
        for (int k = 0; k < 4; ++k) {
            bf16x8 bb = *(const bf16x8*)&wb[41216 + o * 128 + k * 32 + quad * 8];
#pragma unroll
            for (int mt = 0; mt < 4; ++mt) {
                bf16x8 a = *(const bf16x8*)&s_h2[(mt * 16 + lo) * 136 + k * 32 + quad * 8];
                acc[mt] = __builtin_amdgcn_mfma_f32_16x16x32_bf16(a, bb, acc[mt], 0, 0, 0);
            }
        }
        for (int k = 0; k < 6; ++k) {
            bf16x8 bb = *(const bf16x8*)&wb[49472 + o * 192 + k * 32 + quad * 8];
#pragma unroll
            for (int mt = 0; mt < 4; ++mt) {
                bf16x8 a = *(const bf16x8*)&s_s[(mt * 16 + lo) * 200 + k * 32 + quad * 8];
                acc[mt] = __builtin_amdgcn_mfma_f32_16x16x32_bf16(a, bb, acc[mt], 0, 0, 0);
            }
        }
        float bi = pf[49408 + o] + pf[61760 + o];
#pragma unroll
        for (int mt = 0; mt < 4; ++mt)
#pragma unroll
            for (int r = 0; r < 4; ++r)
                s_y[o * 68 + mt * 16 + quad * 4 + r] = acc[mt][r] + bi;
    }
    __syncthreads();

    // phase 4: y = cur + leak * d   (coalesced fp32, identity never bf16-rounded)
    {
        float lk = fminf(fmaxf(leak_p[0], 0.001f), 1000.f);
#pragma unroll
        for (int v = 0; v < 4; ++v) {
            int idx = v * 1024 + t * 4;
            int o = idx >> 6, pix = idx & 63;
            if (pix0 + pix < HW) {
                f32x4 sv = *(const f32x4*)&s_y[o * 68 + pix];
                const float* cb = cur + ((size_t)b * 64 + o) * HW + pix0 + pix;
                float* yb = y + ((size_t)b * 64 + o) * HW + pix0 + pix;
                f32x4 cv = *(const f32x4*)cb;
                f32x4 ov = cv + lk * sv;
                *(f32x4*)yb = ov;
            }
        }
    }
}

// ---------------------------------------------------------------------------
// Kernel 4: downsample = gauss3x3 (zero-pad) then 2x2 mean
// ---------------------------------------------------------------------------
__global__ __launch_bounds__(256) void down_kernel(
    const float* __restrict__ yin, float* __restrict__ outp, int S, int total)
{
    int idx = blockIdx.x * 256 + threadIdx.x;
    if (idx >= total) return;
    const float ga = 0.60653065971263342f;
    const float gs = 1.f / ((1.f + 2.f * ga) * (1.f + 2.f * ga));
    float g1[3] = {ga, 1.f, ga};
    int S2 = S >> 1;
    int ox = idx % S2;
    int r = idx / S2;
    int oy = r % S2;
    int bc = r / S2;
    const float* src = yin + (size_t)bc * S * S;
    float acc = 0.f;
#pragma unroll
    for (int py = 0; py < 2; ++py)
#pragma unroll
        for (int px = 0; px < 2; ++px) {
            int cy = 2 * oy + py, cx = 2 * ox + px;
#pragma unroll
            for (int dy = 0; dy < 3; ++dy) {
                int ay = cy + dy - 1;
                if (ay < 0 || ay >= S) continue;
#pragma unroll
                for (int dx = 0; dx < 3; ++dx) {
                    int ax = cx + dx - 1;
                    if (ax < 0 || ax >= S) continue;
                    acc += g1[dy] * g1[dx] * src[ay * S + ax];
                }
            }
        }
    outp[idx] = acc * 0.25f * gs;
}

// ---------------------------------------------------------------------------
// Kernel 5: head = res_block(outrb) -> spatial mean -> lin_res x2 -> lat
// ---------------------------------------------------------------------------
__global__ __launch_bounds__(256) void head_kernel(
    const float* __restrict__ emb6,
    const float* __restrict__ w0, const float* __restrict__ b0,
    const float* __restrict__ w1, const float* __restrict__ b1,
    const float* __restrict__ l1_sw, const float* __restrict__ l1_sb,
    const float* __restrict__ l1_w1, const float* __restrict__ l1_b1,
    const float* __restrict__ l1_w2, const float* __restrict__ l1_b2,
    const float* __restrict__ l2_w1, const float* __restrict__ l2_b1,
    const float* __restrict__ l2_w2, const float* __restrict__ l2_b2,
    const float* __restrict__ lo_w, const float* __restrict__ lo_b,
    float* __restrict__ lat)
{
    __shared__ float sm_t[256], sm_v[256], sm_r[256];
    __shared__ float sm_h[64];
    __shared__ float sm_u1[1024];
    __shared__ float sm_h1[512], sm_t3[512], sm_h2[512];
    int b = blockIdx.x, t = threadIdx.x;

    sm_t[t] = emb6[b * 256 + t];
    __syncthreads();
    {
        int o = t & 63, p = t >> 6;
        float acc = 0.f;
        for (int k = 0; k < 64; ++k) acc += w0[o * 64 + k] * lrelu(sm_t[k * 4 + p]);
        sm_v[o * 4 + p] = lrelu(acc + b0[o]);
    }
    __syncthreads();
    {
        int o = t & 63, p = t >> 6;
        float acc = 0.f;
        for (int k = 0; k < 64; ++k) acc += w1[o * 64 + k] * sm_v[k * 4 + p];
        sm_r[o * 4 + p] = sm_t[o * 4 + p] + 0.1f * (acc + b1[o]);
    }
    __syncthreads();
    if (t < 64)
        sm_h[t] = 0.25f * (sm_r[t * 4] + sm_r[t * 4 + 1] + sm_r[t * 4 + 2] + sm_r[t * 4 + 3]);
    __syncthreads();

    {
        float acc[4] = {0.f, 0.f, 0.f, 0.f};
        for (int k = 0; k < 64; ++k) {
            float u = lrelu(sm_h[k]);
            const float* r = l1_w1 + k * 1024;
            acc[0] += u * r[t]; acc[1] += u * r[t + 256];
            acc[2] += u * r[t + 512]; acc[3] += u * r[t + 768];
        }
#pragma unroll
        for (int j = 0; j < 4; ++j)
            sm_u1[t + j * 256] = lrelu(acc[j] + l1_b1[t + j * 256]);
    }
    __syncthreads();
    {
        float acc[2] = {0.f, 0.f};
        for (int k = 0; k < 1024; ++k) {
            float u = sm_u1[k];
            acc[0] += u * l1_w2[k * 512 + t];
            acc[1] += u * l1_w2[k * 512 + t + 256];
        }
        float hs[2] = {0.f, 0.f};
        for (int k = 0; k < 64; ++k) {
            float h = sm_h[k];
            hs[0] += h * l1_sw[k * 512 + t];
            hs[1] += h * l1_sw[k * 512 + t + 256];
        }
        sm_h1[t] = hs[0] + l1_sb[t] + 0.1f * (acc[0] + l1_b2[t]);
        sm_h1[t + 256] = hs[1] + l1_sb[t + 256] + 0.1f * (acc[1] + l1_b2[t + 256]);
    }
    __syncthreads();
    {
        float acc[2] = {0.f, 0.f};
        for (int k = 0; k < 512; ++k) {
            float u = lrelu(sm_h1[k]);
            acc[0] += u * l2_w1[k * 512 + t];
            acc[1] += u * l2_w1[k * 512 + t + 256];
        }
        sm_t3[t] = lrelu(acc[0] + l2_b1[t]);
        sm_t3[t + 256] = lrelu(acc[1] + l2_b1[t + 256]);
    }
    __syncthreads();
    {
        float acc[2] = {0.f, 0.f};
        for (int k = 0; k < 512; ++k) {
            float u = sm_t3[k];
            acc[0] += u * l2_w2[k * 512 + t];
            acc[1] += u * l2_w2[k * 512 + t + 256];
        }
        sm_h2[t] = sm_h1[t] + 0.1f * (acc[0] + l2_b2[t]);
        sm_h2[t + 256] = sm_h1[t + 256] + 0.1f * (acc[1] + l2_b2[t + 256]);
    }
    __syncthreads();
    {
        float acc[2] = {0.f, 0.f};
        for (int k = 0; k < 512; ++k) {
            float u = sm_h2[k];
            acc[0] += u * lo_w[k * 512 + t];
            acc[1] += u * lo_w[k * 512 + t + 256];
        }
        lat[b * 512 + t] = acc[0] + lo_b[t];
        lat[b * 512 + t + 256] = acc[1] + lo_b[t + 256];
    }
}

// ---------------------------------------------------------------------------
extern "C" void kernel_launch(void* const* d_in, const int* in_sizes, int n_in,
                              void* d_out, int out_size, void* d_ws, size_t ws_size,
                              hipStream_t stream) {
    const float* x      = (const float*)d_in[0];
    const float* inj    = (const float*)d_in[1];
    const float* leak   = (const float*)d_in[2];
    const float* in_w   = (const float*)d_in[3];
    const float* in_b   = (const float*)d_in[4];
    const float* inrb_w0 = (const float*)d_in[5];
    const float* inrb_b0 = (const float*)d_in[6];
    const float* inrb_w1 = (const float*)d_in[7];
    const float* inrb_b1 = (const float*)d_in[8];
    const float* hyp_w  = (const float*)d_in[9];
    const float* hyp_b  = (const float*)d_in[10];
    const float* outrb_w0 = (const float*)d_in[11];
    const float* outrb_b0 = (const float*)d_in[12];
    const float* outrb_w1 = (const float*)d_in[13];
    const float* outrb_b1 = (const float*)d_in[14];
    const float* l1_sw  = (const float*)d_in[15];
    const float* l1_sb  = (const float*)d_in[16];
    const float* l1_w1  = (const float*)d_in[17];
    const float* l1_b1  = (const float*)d_in[18];
    const float* l1_w2  = (const float*)d_in[19];
    const float* l1_b2  = (const float*)d_in[20];
    const float* l2_w1  = (const float*)d_in[21];
    const float* l2_b1  = (const float*)d_in[22];
    const float* l2_w2  = (const float*)d_in[23];
    const float* l2_b2  = (const float*)d_in[24];
    const float* lo_w   = (const float*)d_in[25];
    const float* lo_b   = (const float*)d_in[26];

    float* out = (float*)d_out;
    float* dyn = (float*)d_ws;                          // 8*61824 floats
    float* ybuf = dyn + (size_t)BATCH * PT;             // 8*64*16384 floats
    short* dyn16 = (short*)(ybuf + (size_t)BATCH * 64 * 16384);  // 8*61824 bf16

    hyper_kernel<<<(PT + 255) / 256, 256, 0, stream>>>(inj, hyp_w, hyp_b, dyn, dyn16);

    size_t cur = 4096;
    stem_kernel<<<BATCH * 256, 256, 0, stream>>>(
        x, in_w, in_b, inrb_w0, inrb_b0, inrb_w1, inrb_b1, out + cur);

    int S = 128, sh = 7;
    for (int i = 0; i < 6; ++i) {
        int tiles = (S * S + 63) / 64;
        iter_kernel<<<BATCH * tiles, 256, 0, stream>>>(
            out + cur, dyn, dyn16, leak, ybuf, S, sh);
        int S2 = S >> 1;
        int total = BATCH * 64 * S2 * S2;
        size_t nxt = cur + (size_t)BATCH * 64 * S * S;
        down_kernel<<<(total + 255) / 256, 256, 0, stream>>>(ybuf, out + nxt, S, total);
        cur = nxt;
        S = S2; sh -= 1;
    }

    head_kernel<<<BATCH, 256, 0, stream>>>(
        out + cur, outrb_w0, outrb_b0, outrb_w1, outrb_b1,
        l1_sw, l1_sb, l1_w1, l1_b1, l1_w2, l1_b2,
        l2_w1, l2_b1, l2_w2, l2_b2, lo_w, lo_b, out);
}

// Round 3
// 664.734 us; speedup vs baseline: 1.9197x; 1.1782x over previous
//
#include <hip/hip_runtime.h>

// Shapes
// B=8, NF=64, FIN=192, FH=128, FOUT=64, LAT=512, P_TOTAL=61824
// dyn param offsets: w_in 0, b_in 24576, w_mid 24704, b_mid 41088,
//                    w_out 41216, b_out 49408, w_sk 49472, b_sk 61760

#define BATCH 8
#define PT 61824

typedef __attribute__((ext_vector_type(8))) short bf16x8;
typedef __attribute__((ext_vector_type(4))) float f32x4;

__device__ __forceinline__ float lrelu(float v) { return v > 0.f ? v : 0.2f * v; }

__device__ __forceinline__ short f2bf(float f) {
    union { float fv; unsigned u; } v; v.fv = f;
    return (short)((v.u + 0x7fffu + ((v.u >> 16) & 1u)) >> 16);  // RNE
}

// ---------------------------------------------------------------------------
// Kernel 1: hypernetwork  dyn[b][p] = sum_k inj[b][k] * hyp_w[k][p] + hyp_b[p]
// ---------------------------------------------------------------------------
__global__ __launch_bounds__(256) void hyper_kernel(
    const float* __restrict__ inj, const float* __restrict__ hw,
    const float* __restrict__ hb, float* __restrict__ dyn,
    short* __restrict__ dyn16)
{
    __shared__ float s_l[512 * 8];  // transposed: s_l[k*8 + b]
    int t = threadIdx.x;
    for (int i = t; i < 4096; i += 256) {
        int b = i >> 9, k = i & 511;
        s_l[k * 8 + b] = inj[i];
    }
    __syncthreads();
    int p = blockIdx.x * 256 + t;
    if (p >= PT) return;
    float acc[8];
#pragma unroll
    for (int b = 0; b < 8; ++b) acc[b] = 0.f;
    for (int k = 0; k < 512; ++k) {
        float w = hw[(size_t)k * PT + p];
        float4 a0 = *(const float4*)&s_l[k * 8];
        float4 a1 = *(const float4*)&s_l[k * 8 + 4];
        acc[0] += a0.x * w; acc[1] += a0.y * w; acc[2] += a0.z * w; acc[3] += a0.w * w;
        acc[4] += a1.x * w; acc[5] += a1.y * w; acc[6] += a1.z * w; acc[7] += a1.w * w;
    }
    float bias = hb[p];
#pragma unroll
    for (int b = 0; b < 8; ++b) {
        float v = acc[b] + bias;
        dyn[(size_t)b * PT + p] = v;
        dyn16[(size_t)b * PT + p] = f2bf(v);
    }
}

// ---------------------------------------------------------------------------
// Kernel 2: stem = conv1x1(x, in_w, in_b) then res_block(inrb) -> emb0
// ---------------------------------------------------------------------------
__global__ __launch_bounds__(256) void stem_kernel(
    const float* __restrict__ x, const float* __restrict__ in_w,
    const float* __restrict__ in_b,
    const float* __restrict__ w0, const float* __restrict__ b0,
    const float* __restrict__ w1, const float* __restrict__ b1,
    float* __restrict__ out0)
{
    const int HW = 128 * 128;
    __shared__ float s_t0[64 * 68];
    __shared__ float s_v[64 * 68];
    const int tilesPer = HW / 64;  // 256
    const int b = blockIdx.x / tilesPer;
    const int tile = blockIdx.x - b * tilesPer;
    const int pix0 = tile * 64;
    const int t = threadIdx.x;

    for (int job = t; job < 64 * 64; job += 256) {
        int p = job & 63, c = job >> 6;
        const float* xb = x + (size_t)b * 3 * HW + pix0 + p;
        float v = in_b[c] + xb[0] * in_w[c * 3] + xb[HW] * in_w[c * 3 + 1]
                + xb[2 * HW] * in_w[c * 3 + 2];
        s_t0[p * 68 + c] = v;
        s_v[p * 68 + c] = lrelu(v);
    }
    __syncthreads();

    const int o = t & 63, g = t >> 6;
    {
        float acc[16];
#pragma unroll
        for (int p = 0; p < 16; ++p) acc[p] = 0.f;
        const float* wr = w0 + o * 64;
        for (int k4 = 0; k4 < 16; ++k4) {
            float4 wv = ((const float4*)wr)[k4];
#pragma unroll
            for (int p = 0; p < 16; ++p) {
                float4 uv = *(const float4*)&s_v[(g * 16 + p) * 68 + k4 * 4];
                acc[p] += wv.x * uv.x + wv.y * uv.y + wv.z * uv.z + wv.w * uv.w;
            }
        }
        __syncthreads();
        float bi = b0[o];
#pragma unroll
        for (int p = 0; p < 16; ++p) s_v[(g * 16 + p) * 68 + o] = lrelu(acc[p] + bi);
    }
    __syncthreads();
    {
        float acc[16];
#pragma unroll
        for (int p = 0; p < 16; ++p) acc[p] = 0.f;
        const float* wr = w1 + o * 64;
        for (int k4 = 0; k4 < 16; ++k4) {
            float4 wv = ((const float4*)wr)[k4];
#pragma unroll
            for (int p = 0; p < 16; ++p) {
                float4 uv = *(const float4*)&s_v[(g * 16 + p) * 68 + k4 * 4];
                acc[p] += wv.x * uv.x + wv.y * uv.y + wv.z * uv.z + wv.w * uv.w;
            }
        }
        float bi = b1[o];
        float* ob = out0 + ((size_t)b * 64 + o) * HW;
#pragma unroll
        for (int p = 0; p < 16; ++p) {
            int pix = pix0 + g * 16 + p;
            ob[pix] = s_t0[(g * 16 + p) * 68 + o] + 0.1f * (acc[p] + bi);
        }
    }
}

// ---------------------------------------------------------------------------
// Kernel 3: fused iteration via MFMA (unchanged from round 2)
// ---------------------------------------------------------------------------
__global__ __launch_bounds__(256) void iter_kernel(
    const float* __restrict__ cur, const float* __restrict__ dynf,
    const short* __restrict__ dynb, const float* __restrict__ leak_p,
    float* __restrict__ y, int S, int sh)
{
    __shared__ short s_s[64 * 200];
    __shared__ short s_h1[64 * 136];
    __shared__ short s_h2[64 * 136];
    float* s_y = (float*)s_h1;

    const int HW = S * S;
    const int tilesPer = (HW + 63) >> 6;
    const int b = blockIdx.x / tilesPer;
    const int tile = blockIdx.x - b * tilesPer;
    const int pix0 = tile * 64;
    const int t = threadIdx.x;
    const float* base = cur + (size_t)b * 64 * HW;

    for (int job = t; job < 4096; job += 256) {
        int p = job & 63, c = job >> 6;
        int gpx = pix0 + p;
        float id = 0.f, sx = 0.f, sy = 0.f;
        if (gpx < HW) {
            int yy = gpx >> sh, xx = gpx & (S - 1);
            const float* ch = base + (size_t)c * HW;
            float v[3][3];
#pragma unroll
            for (int dy = 0; dy < 3; ++dy)
#pragma unroll
                for (int dx = 0; dx < 3; ++dx) {
                    int ay = yy + dy - 1, ax = xx + dx - 1;
                    v[dy][dx] = (ay >= 0 && ay < S && ax >= 0 && ax < S) ? ch[ay * S + ax] : 0.f;
                }
            id = v[1][1];
            sx = (v[0][0] - v[0][2] + 2.f * (v[1][0] - v[1][2]) + v[2][0] - v[2][2]) * 0.125f;
            sy = (v[0][0] + 2.f * v[0][1] + v[0][2] - v[2][0] - 2.f * v[2][1] - v[2][2]) * 0.125f;
        }
        s_s[p * 200 + c] = f2bf(id);
        s_s[p * 200 + 64 + c] = f2bf(sx);
        s_s[p * 200 + 128 + c] = f2bf(sy);
    }
    __syncthreads();

    const int lane = t & 63, wv = t >> 6;
    const int lo = lane & 15, quad = lane >> 4;
    const short* wb = dynb + (size_t)b * PT;
    const float* pf = dynf + (size_t)b * PT;
    const f32x4 z4 = {0.f, 0.f, 0.f, 0.f};

    {
        f32x4 acc[2][4];
#pragma unroll
        for (int n = 0; n < 2; ++n)
#pragma unroll
            for (int mt = 0; mt < 4; ++mt) acc[n][mt] = z4;
        for (int k = 0; k < 6; ++k) {
            bf16x8 a[4];
#pragma unroll
            for (int mt = 0; mt < 4; ++mt)
                a[mt] = *(const bf16x8*)&s_s[(mt * 16 + lo) * 200 + k * 32 + quad * 8];
#pragma unroll
            for (int n = 0; n < 2; ++n) {
                int o = (wv * 2 + n) * 16 + lo;
                bf16x8 bb = *(const bf16x8*)&wb[o * 192 + k * 32 + quad * 8];
#pragma unroll
                for (int mt = 0; mt < 4; ++mt)
                    acc[n][mt] = __builtin_amdgcn_mfma_f32_16x16x32_bf16(a[mt], bb, acc[n][mt], 0, 0, 0);
            }
        }
#pragma unroll
        for (int n = 0; n < 2; ++n) {
            int o = (wv * 2 + n) * 16 + lo;
            float bi = pf[24576 + o];
#pragma unroll
            for (int mt = 0; mt < 4; ++mt)
#pragma unroll
                for (int r = 0; r < 4; ++r)
                    s_h1[(mt * 16 + quad * 4 + r) * 136 + o] = f2bf(lrelu(acc[n][mt][r] + bi));
        }
    }
    __syncthreads();

    {
        f32x4 acc[2][4];
#pragma unroll
        for (int n = 0; n < 2; ++n)
#pragma unroll
            for (int mt = 0; mt < 4; ++mt) acc[n][mt] = z4;
        for (int k = 0; k < 4; ++k) {
            bf16x8 a[4];
#pragma unroll
            for (int mt = 0; mt < 4; ++mt)
                a[mt] = *(const bf16x8*)&s_h1[(mt * 16 + lo) * 136 + k * 32 + quad * 8];
#pragma unroll
            for (int n = 0; n < 2; ++n) {
                int o = (wv * 2 + n) * 16 + lo;
                bf16x8 bb = *(const bf16x8*)&wb[24704 + o * 128 + k * 32 + quad * 8];
#pragma unroll
                for (int mt = 0; mt < 4; ++mt)
                    acc[n][mt] = __builtin_amdgcn_mfma_f32_16x16x32_bf16(a[mt], bb, acc[n][mt], 0, 0, 0);
            }
        }
        __syncthreads();
#pragma unroll
        for (int n = 0; n < 2; ++n) {
            int o = (wv * 2 + n) * 16 + lo;
            float bi = pf[41088 + o];
#pragma unroll
            for (int mt = 0; mt < 4; ++mt)
#pragma unroll
                for (int r = 0; r < 4; ++r)
                    s_h2[(mt * 16 + quad * 4 + r) * 136 + o] = f2bf(lrelu(acc[n][mt][r] + bi));
        }
    }
    __syncthreads();

    {
        f32x4 acc[4];
#pragma unroll
        for (int mt = 0; mt < 4; ++mt) acc[mt] = z4;
        int o = wv * 16 + lo;
        for (int k = 0; k < 4; ++k) {
            bf16x8 bb = *(const bf16x8*)&wb[41216 + o * 128 + k * 32 + quad * 8];
#pragma unroll
            for (int mt = 0; mt < 4; ++mt) {
                bf16x8 a = *(const bf16x8*)&s_h2[(mt * 16 + lo) * 136 + k * 32 + quad * 8];
                acc[mt] = __builtin_amdgcn_mfma_f32_16x16x32_bf16(a, bb, acc[mt], 0, 0, 0);
            }
        }
        for (int k = 0; k < 6; ++k) {
            bf16x8 bb = *(const bf16x8*)&wb[49472 + o * 192 + k * 32 + quad * 8];
#pragma unroll
            for (int mt = 0; mt < 4; ++mt) {
                bf16x8 a = *(const bf16x8*)&s_s[(mt * 16 + lo) * 200 + k * 32 + quad * 8];
                acc[mt] = __builtin_amdgcn_mfma_f32_16x16x32_bf16(a, bb, acc[mt], 0, 0, 0);
            }
        }
        float bi = pf[49408 + o] + pf[61760 + o];
#pragma unroll
        for (int mt = 0; mt < 4; ++mt)
#pragma unroll
            for (int r = 0; r < 4; ++r)
                s_y[o * 68 + mt * 16 + quad * 4 + r] = acc[mt][r] + bi;
    }
    __syncthreads();

    {
        float lk = fminf(fmaxf(leak_p[0], 0.001f), 1000.f);
#pragma unroll
        for (int v = 0; v < 4; ++v) {
            int idx = v * 1024 + t * 4;
            int o = idx >> 6, pix = idx & 63;
            if (pix0 + pix < HW) {
                f32x4 sv = *(const f32x4*)&s_y[o * 68 + pix];
                const float* cb = cur + ((size_t)b * 64 + o) * HW + pix0 + pix;
                float* yb = y + ((size_t)b * 64 + o) * HW + pix0 + pix;
                f32x4 cv = *(const f32x4*)cb;
                f32x4 ov = cv + lk * sv;
                *(f32x4*)yb = ov;
            }
        }
    }
}

// ---------------------------------------------------------------------------
// Kernel 4: downsample = gauss3x3 (zero-pad) then 2x2 mean
// ---------------------------------------------------------------------------
__global__ __launch_bounds__(256) void down_kernel(
    const float* __restrict__ yin, float* __restrict__ outp, int S, int total)
{
    int idx = blockIdx.x * 256 + threadIdx.x;
    if (idx >= total) return;
    const float ga = 0.60653065971263342f;
    const float gs = 1.f / ((1.f + 2.f * ga) * (1.f + 2.f * ga));
    float g1[3] = {ga, 1.f, ga};
    int S2 = S >> 1;
    int ox = idx % S2;
    int r = idx / S2;
    int oy = r % S2;
    int bc = r / S2;
    const float* src = yin + (size_t)bc * S * S;
    float acc = 0.f;
#pragma unroll
    for (int py = 0; py < 2; ++py)
#pragma unroll
        for (int px = 0; px < 2; ++px) {
            int cy = 2 * oy + py, cx = 2 * ox + px;
#pragma unroll
            for (int dy = 0; dy < 3; ++dy) {
                int ay = cy + dy - 1;
                if (ay < 0 || ay >= S) continue;
#pragma unroll
                for (int dx = 0; dx < 3; ++dx) {
                    int ax = cx + dx - 1;
                    if (ax < 0 || ax >= S) continue;
                    acc += g1[dy] * g1[dx] * src[ay * S + ax];
                }
            }
        }
    outp[idx] = acc * 0.25f * gs;
}

// ---------------------------------------------------------------------------
// Head pipeline. Scratch layout (floats): h[512] t1[8192] h1[4096] z3[4096] h2[4096]
// h1/z3/h2/lat are zeroed by hipMemsetAsync; partial sums land via atomicAdd.
// ---------------------------------------------------------------------------

// Stage A: res_block(outrb) on 2x2 maps + spatial mean -> h[8][64]
__global__ __launch_bounds__(256) void head_a_kernel(
    const float* __restrict__ emb6,
    const float* __restrict__ w0, const float* __restrict__ b0,
    const float* __restrict__ w1, const float* __restrict__ b1,
    float* __restrict__ h)
{
    __shared__ float sm_t[256], sm_v[256], sm_r[256];
    int b = blockIdx.x, t = threadIdx.x;
    sm_t[t] = emb6[b * 256 + t];  // [c*4 + p]
    __syncthreads();
    {
        int o = t & 63, p = t >> 6;
        float acc = 0.f;
        for (int k = 0; k < 64; ++k) acc += w0[o * 64 + k] * lrelu(sm_t[k * 4 + p]);
        sm_v[o * 4 + p] = lrelu(acc + b0[o]);
    }
    __syncthreads();
    {
        int o = t & 63, p = t >> 6;
        float acc = 0.f;
        for (int k = 0; k < 64; ++k) acc += w1[o * 64 + k] * sm_v[k * 4 + p];
        sm_r[o * 4 + p] = sm_t[o * 4 + p] + 0.1f * (acc + b1[o]);
    }
    __syncthreads();
    if (t < 64)
        h[b * 64 + t] = 0.25f * (sm_r[t * 4] + sm_r[t * 4 + 1] + sm_r[t * 4 + 2] + sm_r[t * 4 + 3]);
}

// Stage B: t1[8][1024] = lrelu(lrelu(h) @ l1_w1 + l1_b1)   K=64
__global__ __launch_bounds__(256) void head_b_kernel(
    const float* __restrict__ h, const float* __restrict__ w,
    const float* __restrict__ bias, float* __restrict__ t1)
{
    __shared__ float s_h[64];
    int id = blockIdx.x * 256 + threadIdx.x;   // 8192 total
    int b = id >> 10, o = id & 1023;
    if (threadIdx.x < 64) s_h[threadIdx.x] = lrelu(h[b * 64 + threadIdx.x]);
    __syncthreads();
    float acc = 0.f;
    for (int k = 0; k < 64; ++k) acc += s_h[k] * w[k * 1024 + o];
    t1[b * 1024 + o] = lrelu(acc + bias[o]);
}

// Stage C: h1[8][512] += skip-chunk0 + 0.1 * (t1-chunk @ l1_w2)
// grid = 2 o-blocks x 8 k-chunks (chunk=128)
__global__ __launch_bounds__(256) void head_c_kernel(
    const float* __restrict__ h, const float* __restrict__ t1,
    const float* __restrict__ sw, const float* __restrict__ sb,
    const float* __restrict__ w2, const float* __restrict__ b2,
    float* __restrict__ h1)
{
    __shared__ float s_t[8 * 128];
    __shared__ float s_h[8 * 64];
    int oblk = blockIdx.x & 1, chunk = blockIdx.x >> 1;
    int t = threadIdx.x;
    int o = oblk * 256 + t;
    for (int j = t; j < 1024; j += 256) {
        int b = j >> 7, kk = j & 127;
        s_t[j] = t1[b * 1024 + chunk * 128 + kk];
    }
    if (chunk == 0)
        for (int j = t; j < 512; j += 256) s_h[j] = h[j];
    __syncthreads();
    float acc[8];
#pragma unroll
    for (int b = 0; b < 8; ++b) acc[b] = 0.f;
    for (int kk = 0; kk < 128; ++kk) {
        float wv = w2[(chunk * 128 + kk) * 512 + o];
#pragma unroll
        for (int b = 0; b < 8; ++b) acc[b] += s_t[b * 128 + kk] * wv;
    }
#pragma unroll
    for (int b = 0; b < 8; ++b) acc[b] *= 0.1f;
    if (chunk == 0) {
        for (int k = 0; k < 64; ++k) {
            float wv = sw[k * 512 + o];
#pragma unroll
            for (int b = 0; b < 8; ++b) acc[b] += s_h[b * 64 + k] * wv;
        }
        float c0 = sb[o] + 0.1f * b2[o];
#pragma unroll
        for (int b = 0; b < 8; ++b) acc[b] += c0;
    }
#pragma unroll
    for (int b = 0; b < 8; ++b) atomicAdd(&h1[b * 512 + o], acc[b]);
}

// Stage D: z3[8][512] += lrelu(h1)-chunk @ l2_w1 (+ l2_b1 on chunk0)  K=512
__global__ __launch_bounds__(256) void head_d_kernel(
    const float* __restrict__ h1, const float* __restrict__ w,
    const float* __restrict__ bias, float* __restrict__ z3)
{
    __shared__ float s_u[8 * 64];
    int oblk = blockIdx.x & 1, chunk = blockIdx.x >> 1;  // 8 chunks of 64
    int t = threadIdx.x;
    int o = oblk * 256 + t;
    for (int j = t; j < 512; j += 256) {
        int b = j >> 6, kk = j & 63;
        s_u[j] = lrelu(h1[b * 512 + chunk * 64 + kk]);
    }
    __syncthreads();
    float acc[8];
#pragma unroll
    for (int b = 0; b < 8; ++b) acc[b] = 0.f;
    for (int kk = 0; kk < 64; ++kk) {
        float wv = w[(chunk * 64 + kk) * 512 + o];
#pragma unroll
        for (int b = 0; b < 8; ++b) acc[b] += s_u[b * 64 + kk] * wv;
    }
    if (chunk == 0) {
        float c0 = bias[o];
#pragma unroll
        for (int b = 0; b < 8; ++b) acc[b] += c0;
    }
#pragma unroll
    for (int b = 0; b < 8; ++b) atomicAdd(&z3[b * 512 + o], acc[b]);
}

// Stage E: h2[8][512] += 0.1*(lrelu(z3)-chunk @ l2_w2) (+ h1 + 0.1*l2_b2 on chunk0)
__global__ __launch_bounds__(256) void head_e_kernel(
    const float* __restrict__ h1, const float* __restrict__ z3,
    const float* __restrict__ w, const float* __restrict__ bias,
    float* __restrict__ h2)
{
    __shared__ float s_u[8 * 64];
    int oblk = blockIdx.x & 1, chunk = blockIdx.x >> 1;
    int t = threadIdx.x;
    int o = oblk * 256 + t;
    for (int j = t; j < 512; j += 256) {
        int b = j >> 6, kk = j & 63;
        s_u[j] = lrelu(z3[b * 512 + chunk * 64 + kk]);
    }
    __syncthreads();
    float acc[8];
#pragma unroll
    for (int b = 0; b < 8; ++b) acc[b] = 0.f;
    for (int kk = 0; kk < 64; ++kk) {
        float wv = w[(chunk * 64 + kk) * 512 + o];
#pragma unroll
        for (int b = 0; b < 8; ++b) acc[b] += s_u[b * 64 + kk] * wv;
    }
#pragma unroll
    for (int b = 0; b < 8; ++b) acc[b] *= 0.1f;
    if (chunk == 0) {
        float c0 = 0.1f * bias[o];
#pragma unroll
        for (int b = 0; b < 8; ++b) acc[b] += h1[b * 512 + o] + c0;
    }
#pragma unroll
    for (int b = 0; b < 8; ++b) atomicAdd(&h2[b * 512 + o], acc[b]);
}

// Stage F: lat[8][512] += h2-chunk @ lo_w (+ lo_b on chunk0)
__global__ __launch_bounds__(256) void head_f_kernel(
    const float* __restrict__ h2, const float* __restrict__ w,
    const float* __restrict__ bias, float* __restrict__ lat)
{
    __shared__ float s_u[8 * 64];
    int oblk = blockIdx.x & 1, chunk = blockIdx.x >> 1;
    int t = threadIdx.x;
    int o = oblk * 256 + t;
    for (int j = t; j < 512; j += 256) {
        int b = j >> 6, kk = j & 63;
        s_u[j] = h2[b * 512 + chunk * 64 + kk];
    }
    __syncthreads();
    float acc[8];
#pragma unroll
    for (int b = 0; b < 8; ++b) acc[b] = 0.f;
    for (int kk = 0; kk < 64; ++kk) {
        float wv = w[(chunk * 64 + kk) * 512 + o];
#pragma unroll
        for (int b = 0; b < 8; ++b) acc[b] += s_u[b * 64 + kk] * wv;
    }
    if (chunk == 0) {
        float c0 = bias[o];
#pragma unroll
        for (int b = 0; b < 8; ++b) acc[b] += c0;
    }
#pragma unroll
    for (int b = 0; b < 8; ++b) atomicAdd(&lat[b * 512 + o], acc[b]);
}

// ---------------------------------------------------------------------------
extern "C" void kernel_launch(void* const* d_in, const int* in_sizes, int n_in,
                              void* d_out, int out_size, void* d_ws, size_t ws_size,
                              hipStream_t stream) {
    const float* x      = (const float*)d_in[0];
    const float* inj    = (const float*)d_in[1];
    const float* leak   = (const float*)d_in[2];
    const float* in_w   = (const float*)d_in[3];
    const float* in_b   = (const float*)d_in[4];
    const float* inrb_w0 = (const float*)d_in[5];
    const float* inrb_b0 = (const float*)d_in[6];
    const float* inrb_w1 = (const float*)d_in[7];
    const float* inrb_b1 = (const float*)d_in[8];
    const float* hyp_w  = (const float*)d_in[9];
    const float* hyp_b  = (const float*)d_in[10];
    const float* outrb_w0 = (const float*)d_in[11];
    const float* outrb_b0 = (const float*)d_in[12];
    const float* outrb_w1 = (const float*)d_in[13];
    const float* outrb_b1 = (const float*)d_in[14];
    const float* l1_sw  = (const float*)d_in[15];
    const float* l1_sb  = (const float*)d_in[16];
    const float* l1_w1  = (const float*)d_in[17];
    const float* l1_b1  = (const float*)d_in[18];
    const float* l1_w2  = (const float*)d_in[19];
    const float* l1_b2  = (const float*)d_in[20];
    const float* l2_w1  = (const float*)d_in[21];
    const float* l2_b1  = (const float*)d_in[22];
    const float* l2_w2  = (const float*)d_in[23];
    const float* l2_b2  = (const float*)d_in[24];
    const float* lo_w   = (const float*)d_in[25];
    const float* lo_b   = (const float*)d_in[26];

    float* out = (float*)d_out;
    float* dyn = (float*)d_ws;                          // 8*61824 f
    float* ybuf = dyn + (size_t)BATCH * PT;             // 8*64*16384 f
    short* dyn16 = (short*)(ybuf + (size_t)BATCH * 64 * 16384);  // 8*61824 bf16
    float* hbuf = (float*)(dyn16 + (size_t)BATCH * PT);
    float* t1buf = hbuf + 512;
    float* h1buf = t1buf + 8192;
    float* z3buf = h1buf + 4096;
    float* h2buf = z3buf + 4096;

    // zero the atomic-accumulated buffers (h1, z3, h2) and the lat output
    hipMemsetAsync(h1buf, 0, (4096 * 3) * sizeof(float), stream);
    hipMemsetAsync(out, 0, 4096 * sizeof(float), stream);

    hyper_kernel<<<(PT + 255) / 256, 256, 0, stream>>>(inj, hyp_w, hyp_b, dyn, dyn16);

    size_t cur = 4096;
    stem_kernel<<<BATCH * 256, 256, 0, stream>>>(
        x, in_w, in_b, inrb_w0, inrb_b0, inrb_w1, inrb_b1, out + cur);

    int S = 128, sh = 7;
    for (int i = 0; i < 6; ++i) {
        int tiles = (S * S + 63) / 64;
        iter_kernel<<<BATCH * tiles, 256, 0, stream>>>(
            out + cur, dyn, dyn16, leak, ybuf, S, sh);
        int S2 = S >> 1;
        int total = BATCH * 64 * S2 * S2;
        size_t nxt = cur + (size_t)BATCH * 64 * S * S;
        down_kernel<<<(total + 255) / 256, 256, 0, stream>>>(ybuf, out + nxt, S, total);
        cur = nxt;
        S = S2; sh -= 1;
    }

    // head pipeline
    head_a_kernel<<<BATCH, 256, 0, stream>>>(
        out + cur, outrb_w0, outrb_b0, outrb_w1, outrb_b1, hbuf);
    head_b_kernel<<<32, 256, 0, stream>>>(hbuf, l1_w1, l1_b1, t1buf);
    head_c_kernel<<<16, 256, 0, stream>>>(hbuf, t1buf, l1_sw, l1_sb, l1_w2, l1_b2, h1buf);
    head_d_kernel<<<16, 256, 0, stream>>>(h1buf, l2_w1, l2_b1, z3buf);
    head_e_kernel<<<16, 256, 0, stream>>>(h1buf, z3buf, l2_w2, l2_b2, h2buf);
    head_f_kernel<<<16, 256, 0, stream>>>(h2buf, lo_w, lo_b, out);
}

// Round 4
// 577.061 us; speedup vs baseline: 2.2114x; 1.1519x over previous
//
#include <hip/hip_runtime.h>

// Shapes
// B=8, NF=64, FIN=192, FH=128, FOUT=64, LAT=512, P_TOTAL=61824
// dyn param offsets: w_in 0, b_in 24576, w_mid 24704, b_mid 41088,
//                    w_out 41216, b_out 49408, w_sk 49472, b_sk 61760

#define BATCH 8
#define PT 61824

typedef __attribute__((ext_vector_type(8))) short bf16x8;
typedef __attribute__((ext_vector_type(4))) float f32x4;

__device__ __forceinline__ float lrelu(float v) { return v > 0.f ? v : 0.2f * v; }

__device__ __forceinline__ short f2bf(float f) {
    union { float fv; unsigned u; } v; v.fv = f;
    return (short)((v.u + 0x7fffu + ((v.u >> 16) & 1u)) >> 16);  // RNE
}

// ---------------------------------------------------------------------------
// Kernel 1: hypernetwork  dyn[b][p] = sum_k inj[b][k] * hyp_w[k][p] + hyp_b[p]
// ---------------------------------------------------------------------------
__global__ __launch_bounds__(256) void hyper_kernel(
    const float* __restrict__ inj, const float* __restrict__ hw,
    const float* __restrict__ hb, float* __restrict__ dyn,
    short* __restrict__ dyn16)
{
    __shared__ float s_l[512 * 8];  // transposed: s_l[k*8 + b]
    int t = threadIdx.x;
    for (int i = t; i < 4096; i += 256) {
        int b = i >> 9, k = i & 511;
        s_l[k * 8 + b] = inj[i];
    }
    __syncthreads();
    int p = blockIdx.x * 256 + t;
    if (p >= PT) return;
    float acc[8];
#pragma unroll
    for (int b = 0; b < 8; ++b) acc[b] = 0.f;
    for (int k = 0; k < 512; ++k) {
        float w = hw[(size_t)k * PT + p];
        float4 a0 = *(const float4*)&s_l[k * 8];
        float4 a1 = *(const float4*)&s_l[k * 8 + 4];
        acc[0] += a0.x * w; acc[1] += a0.y * w; acc[2] += a0.z * w; acc[3] += a0.w * w;
        acc[4] += a1.x * w; acc[5] += a1.y * w; acc[6] += a1.z * w; acc[7] += a1.w * w;
    }
    float bias = hb[p];
#pragma unroll
    for (int b = 0; b < 8; ++b) {
        float v = acc[b] + bias;
        dyn[(size_t)b * PT + p] = v;
        dyn16[(size_t)b * PT + p] = f2bf(v);
    }
}

// ---------------------------------------------------------------------------
// Kernel 2: stem = conv1x1(x, in_w, in_b) then res_block(inrb) -> emb0
// ---------------------------------------------------------------------------
__global__ __launch_bounds__(256) void stem_kernel(
    const float* __restrict__ x, const float* __restrict__ in_w,
    const float* __restrict__ in_b,
    const float* __restrict__ w0, const float* __restrict__ b0,
    const float* __restrict__ w1, const float* __restrict__ b1,
    float* __restrict__ out0)
{
    const int HW = 128 * 128;
    __shared__ float s_t0[64 * 68];
    __shared__ float s_v[64 * 68];
    const int tilesPer = HW / 64;  // 256
    const int b = blockIdx.x / tilesPer;
    const int tile = blockIdx.x - b * tilesPer;
    const int pix0 = tile * 64;
    const int t = threadIdx.x;

    for (int job = t; job < 64 * 64; job += 256) {
        int p = job & 63, c = job >> 6;
        const float* xb = x + (size_t)b * 3 * HW + pix0 + p;
        float v = in_b[c] + xb[0] * in_w[c * 3] + xb[HW] * in_w[c * 3 + 1]
                + xb[2 * HW] * in_w[c * 3 + 2];
        s_t0[p * 68 + c] = v;
        s_v[p * 68 + c] = lrelu(v);
    }
    __syncthreads();

    const int o = t & 63, g = t >> 6;
    {
        float acc[16];
#pragma unroll
        for (int p = 0; p < 16; ++p) acc[p] = 0.f;
        const float* wr = w0 + o * 64;
        for (int k4 = 0; k4 < 16; ++k4) {
            float4 wv = ((const float4*)wr)[k4];
#pragma unroll
            for (int p = 0; p < 16; ++p) {
                float4 uv = *(const float4*)&s_v[(g * 16 + p) * 68 + k4 * 4];
                acc[p] += wv.x * uv.x + wv.y * uv.y + wv.z * uv.z + wv.w * uv.w;
            }
        }
        __syncthreads();
        float bi = b0[o];
#pragma unroll
        for (int p = 0; p < 16; ++p) s_v[(g * 16 + p) * 68 + o] = lrelu(acc[p] + bi);
    }
    __syncthreads();
    {
        float acc[16];
#pragma unroll
        for (int p = 0; p < 16; ++p) acc[p] = 0.f;
        const float* wr = w1 + o * 64;
        for (int k4 = 0; k4 < 16; ++k4) {
            float4 wv = ((const float4*)wr)[k4];
#pragma unroll
            for (int p = 0; p < 16; ++p) {
                float4 uv = *(const float4*)&s_v[(g * 16 + p) * 68 + k4 * 4];
                acc[p] += wv.x * uv.x + wv.y * uv.y + wv.z * uv.z + wv.w * uv.w;
            }
        }
        float bi = b1[o];
        float* ob = out0 + ((size_t)b * 64 + o) * HW;
#pragma unroll
        for (int p = 0; p < 16; ++p) {
            int pix = pix0 + g * 16 + p;
            ob[pix] = s_t0[(g * 16 + p) * 68 + o] + 0.1f * (acc[p] + bi);
        }
    }
}

// ---------------------------------------------------------------------------
// Kernel 3: fused iteration via MFMA, templated on tile size (MT m-tiles of 16 px)
// block = (sample, MT*16-pixel tile), 256 threads = 4 waves
// phase0: sobel via lane-shuffle, conflict-free packed LDS writes
// s_h holds h1 then h2 (register round-trip); s_y aliases s_s
// ---------------------------------------------------------------------------
template<int MT>
__global__ __launch_bounds__(256) void iter_kernel(
    const float* __restrict__ cur, const float* __restrict__ dynf,
    const short* __restrict__ dynb, const float* __restrict__ leak_p,
    float* __restrict__ y, int S, int sh)
{
    constexpr int PX = MT * 16;
    constexpr int SY = (MT == 4) ? 68 : 20;   // fp32 out stride (words)
    __shared__ short s_s[PX * 200];   // bf16 sobel [pix][192], stride 200
    __shared__ short s_h[PX * 136];   // bf16 h1 then h2 [pix][128], stride 136
    float* s_y = (float*)s_s;         // fp32 d [o][px]

    const int HW = S * S;
    const int tilesPer = HW / PX;
    const int b = blockIdx.x / tilesPer;
    const int tile = blockIdx.x - b * tilesPer;
    const int pix0 = tile * PX;
    const int t = threadIdx.x;
    const int l = t & 63, w = t >> 6;
    const int lp = l & 15, lq = l >> 4;
    const float* base = cur + (size_t)b * 64 * HW;

    // ---- phase 0: sin_sobel via shuffles ----
    {
        const int p = (MT == 4) ? (lp + 16 * w) : lp;
        const int gpx = pix0 + p;
        const int row = gpx >> sh;
        const int x = gpx & (S - 1);
        const bool rm = (row > 0), rp = (row < S - 1);
        const bool le = (lp == 0) && (x > 0);
        const bool re = (lp == 15) && (x < S - 1);
        const int iters = (MT == 4) ? 8 : 2;
        int* s32 = (int*)s_s;
        for (int i = 0; i < iters; ++i) {
            const int cp = (MT == 4) ? (lq + 4 * i) : (lq + 4 * w + 16 * i);
            unsigned pk_id = 0, pk_sx = 0, pk_sy = 0;
#pragma unroll
            for (int cc = 0; cc < 2; ++cc) {
                const int c = 2 * cp + cc;
                const float* ch = base + (size_t)c * HW + row * S;
                float vm = rm ? ch[x - S] : 0.f;
                float v0 = ch[x];
                float vp = rp ? ch[x + S] : 0.f;
                float elm = 0.f, el0 = 0.f, elp = 0.f, erm = 0.f, er0 = 0.f, erp = 0.f;
                if (le) { elm = rm ? ch[x - 1 - S] : 0.f; el0 = ch[x - 1]; elp = rp ? ch[x - 1 + S] : 0.f; }
                if (re) { erm = rm ? ch[x + 1 - S] : 0.f; er0 = ch[x + 1]; erp = rp ? ch[x + 1 + S] : 0.f; }
                float Lm = __shfl(vm, l - 1), L0 = __shfl(v0, l - 1), Lp = __shfl(vp, l - 1);
                float Rm = __shfl(vm, l + 1), R0 = __shfl(v0, l + 1), Rp = __shfl(vp, l + 1);
                if (lp == 0)  { Lm = elm; L0 = el0; Lp = elp; }
                if (lp == 15) { Rm = erm; R0 = er0; Rp = erp; }
                if (x == 0)     { Lm = 0.f; L0 = 0.f; Lp = 0.f; }
                if (x == S - 1) { Rm = 0.f; R0 = 0.f; Rp = 0.f; }
                float sx = (Lm - Rm + 2.f * (L0 - R0) + Lp - Rp) * 0.125f;
                float sy = (Lm + 2.f * vm + Rm - Lp - 2.f * vp - Rp) * 0.125f;
                unsigned hid = (unsigned short)f2bf(v0);
                unsigned hsx = (unsigned short)f2bf(sx);
                unsigned hsy = (unsigned short)f2bf(sy);
                pk_id |= hid << (16 * cc);
                pk_sx |= hsx << (16 * cc);
                pk_sy |= hsy << (16 * cc);
            }
            s32[p * 100 + cp] = (int)pk_id;
            s32[p * 100 + 32 + cp] = (int)pk_sx;
            s32[p * 100 + 64 + cp] = (int)pk_sy;
        }
    }
    __syncthreads();

    const short* wb = dynb + (size_t)b * PT;
    const float* pf = dynf + (size_t)b * PT;
    const f32x4 z4 = {0.f, 0.f, 0.f, 0.f};

    // ---- phase 1: h1 = act(w_in * s + b_in)   O=128 (2 ntiles/wave), K=192 ----
    {
        f32x4 acc[2][MT];
#pragma unroll
        for (int n = 0; n < 2; ++n)
#pragma unroll
            for (int mt = 0; mt < MT; ++mt) acc[n][mt] = z4;
        for (int k = 0; k < 6; ++k) {
            bf16x8 a[MT];
#pragma unroll
            for (int mt = 0; mt < MT; ++mt)
                a[mt] = *(const bf16x8*)&s_s[(mt * 16 + lp) * 200 + k * 32 + lq * 8];
#pragma unroll
            for (int n = 0; n < 2; ++n) {
                int o = (w * 2 + n) * 16 + lp;
                bf16x8 bb = *(const bf16x8*)&wb[o * 192 + k * 32 + lq * 8];
#pragma unroll
                for (int mt = 0; mt < MT; ++mt)
                    acc[n][mt] = __builtin_amdgcn_mfma_f32_16x16x32_bf16(a[mt], bb, acc[n][mt], 0, 0, 0);
            }
        }
#pragma unroll
        for (int n = 0; n < 2; ++n) {
            int o = (w * 2 + n) * 16 + lp;
            float bi = pf[24576 + o];
#pragma unroll
            for (int mt = 0; mt < MT; ++mt)
#pragma unroll
                for (int r = 0; r < 4; ++r)
                    s_h[(mt * 16 + lq * 4 + r) * 136 + o] = f2bf(lrelu(acc[n][mt][r] + bi));
        }
    }
    __syncthreads();

    // ---- phase 2: h2 = act(w_mid * h1 + b_mid)   O=128, K=128 (in-place via regs) ----
    {
        f32x4 acc[2][MT];
#pragma unroll
        for (int n = 0; n < 2; ++n)
#pragma unroll
            for (int mt = 0; mt < MT; ++mt) acc[n][mt] = z4;
        for (int k = 0; k < 4; ++k) {
            bf16x8 a[MT];
#pragma unroll
            for (int mt = 0; mt < MT; ++mt)
                a[mt] = *(const bf16x8*)&s_h[(mt * 16 + lp) * 136 + k * 32 + lq * 8];
#pragma unroll
            for (int n = 0; n < 2; ++n) {
                int o = (w * 2 + n) * 16 + lp;
                bf16x8 bb = *(const bf16x8*)&wb[24704 + o * 128 + k * 32 + lq * 8];
#pragma unroll
                for (int mt = 0; mt < MT; ++mt)
                    acc[n][mt] = __builtin_amdgcn_mfma_f32_16x16x32_bf16(a[mt], bb, acc[n][mt], 0, 0, 0);
            }
        }
        __syncthreads();  // all h1 reads complete before overwrite
#pragma unroll
        for (int n = 0; n < 2; ++n) {
            int o = (w * 2 + n) * 16 + lp;
            float bi = pf[41088 + o];
#pragma unroll
            for (int mt = 0; mt < MT; ++mt)
#pragma unroll
                for (int r = 0; r < 4; ++r)
                    s_h[(mt * 16 + lq * 4 + r) * 136 + o] = f2bf(lrelu(acc[n][mt][r] + bi));
        }
    }
    __syncthreads();

    // ---- phase 3: d = w_out*h2 + w_sk*s + (b_out + b_sk)   O=64 ----
    {
        f32x4 acc[MT];
#pragma unroll
        for (int mt = 0; mt < MT; ++mt) acc[mt] = z4;
        int o = w * 16 + lp;
        for (int k = 0; k < 4; ++k) {
            bf16x8 bb = *(const bf16x8*)&wb[41216 + o * 128 + k * 32 + lq * 8];
#pragma unroll
            for (int mt = 0; mt < MT; ++mt) {
                bf16x8 a = *(const bf16x8*)&s_h[(mt * 16 + lp) * 136 + k * 32 + lq * 8];
                acc[mt] = __builtin_amdgcn_mfma_f32_16x16x32_bf16(a, bb, acc[mt], 0, 0, 0);
            }
        }
        for (int k = 0; k < 6; ++k) {
            bf16x8 bb = *(const bf16x8*)&wb[49472 + o * 192 + k * 32 + lq * 8];
#pragma unroll
            for (int mt = 0; mt < MT; ++mt) {
                bf16x8 a = *(const bf16x8*)&s_s[(mt * 16 + lp) * 200 + k * 32 + lq * 8];
                acc[mt] = __builtin_amdgcn_mfma_f32_16x16x32_bf16(a, bb, acc[mt], 0, 0, 0);
            }
        }
        float bi = pf[49408 + o] + pf[61760 + o];
        __syncthreads();  // all s_s reads complete before s_y (aliased) writes
#pragma unroll
        for (int mt = 0; mt < MT; ++mt)
#pragma unroll
            for (int r = 0; r < 4; ++r)
                s_y[o * SY + mt * 16 + lq * 4 + r] = acc[mt][r] + bi;
    }
    __syncthreads();

    // ---- phase 4: y = cur + leak * d  (coalesced fp32) ----
    {
        float lk = fminf(fmaxf(leak_p[0], 0.001f), 1000.f);
        if (MT == 4) {
#pragma unroll
            for (int v = 0; v < 4; ++v) {
                int idx = v * 1024 + t * 4;
                int o = idx >> 6, px = idx & 63;
                f32x4 sv = *(const f32x4*)&s_y[o * SY + px];
                const float* cb = cur + ((size_t)b * 64 + o) * HW + pix0 + px;
                float* yb = y + ((size_t)b * 64 + o) * HW + pix0 + px;
                f32x4 cv = *(const f32x4*)cb;
                *(f32x4*)yb = cv + lk * sv;
            }
        } else {
            int o = t >> 2, px = (t & 3) * 4;
            f32x4 sv = *(const f32x4*)&s_y[o * SY + px];
            const float* cb = cur + ((size_t)b * 64 + o) * HW + pix0 + px;
            float* yb = y + ((size_t)b * 64 + o) * HW + pix0 + px;
            f32x4 cv = *(const f32x4*)cb;
            *(f32x4*)yb = cv + lk * sv;
        }
    }
}

// ---------------------------------------------------------------------------
// Kernel 4: downsample = gauss3x3 (zero-pad) then 2x2 mean
// ---------------------------------------------------------------------------
__global__ __launch_bounds__(256) void down_kernel(
    const float* __restrict__ yin, float* __restrict__ outp, int S, int total)
{
    int idx = blockIdx.x * 256 + threadIdx.x;
    if (idx >= total) return;
    const float ga = 0.60653065971263342f;
    const float gs = 1.f / ((1.f + 2.f * ga) * (1.f + 2.f * ga));
    float g1[3] = {ga, 1.f, ga};
    int S2 = S >> 1;
    int ox = idx % S2;
    int r = idx / S2;
    int oy = r % S2;
    int bc = r / S2;
    const float* src = yin + (size_t)bc * S * S;
    float acc = 0.f;
#pragma unroll
    for (int py = 0; py < 2; ++py)
#pragma unroll
        for (int px = 0; px < 2; ++px) {
            int cy = 2 * oy + py, cx = 2 * ox + px;
#pragma unroll
            for (int dy = 0; dy < 3; ++dy) {
                int ay = cy + dy - 1;
                if (ay < 0 || ay >= S) continue;
#pragma unroll
                for (int dx = 0; dx < 3; ++dx) {
                    int ax = cx + dx - 1;
                    if (ax < 0 || ax >= S) continue;
                    acc += g1[dy] * g1[dx] * src[ay * S + ax];
                }
            }
        }
    outp[idx] = acc * 0.25f * gs;
}

// ---------------------------------------------------------------------------
// Head pipeline (unchanged from round 3)
// ---------------------------------------------------------------------------
__global__ __launch_bounds__(256) void head_a_kernel(
    const float* __restrict__ emb6,
    const float* __restrict__ w0, const float* __restrict__ b0,
    const float* __restrict__ w1, const float* __restrict__ b1,
    float* __restrict__ h)
{
    __shared__ float sm_t[256], sm_v[256], sm_r[256];
    int b = blockIdx.x, t = threadIdx.x;
    sm_t[t] = emb6[b * 256 + t];
    __syncthreads();
    {
        int o = t & 63, p = t >> 6;
        float acc = 0.f;
        for (int k = 0; k < 64; ++k) acc += w0[o * 64 + k] * lrelu(sm_t[k * 4 + p]);
        sm_v[o * 4 + p] = lrelu(acc + b0[o]);
    }
    __syncthreads();
    {
        int o = t & 63, p = t >> 6;
        float acc = 0.f;
        for (int k = 0; k < 64; ++k) acc += w1[o * 64 + k] * sm_v[k * 4 + p];
        sm_r[o * 4 + p] = sm_t[o * 4 + p] + 0.1f * (acc + b1[o]);
    }
    __syncthreads();
    if (t < 64)
        h[b * 64 + t] = 0.25f * (sm_r[t * 4] + sm_r[t * 4 + 1] + sm_r[t * 4 + 2] + sm_r[t * 4 + 3]);
}

__global__ __launch_bounds__(256) void head_b_kernel(
    const float* __restrict__ h, const float* __restrict__ w,
    const float* __restrict__ bias, float* __restrict__ t1)
{
    __shared__ float s_h[64];
    int id = blockIdx.x * 256 + threadIdx.x;
    int b = id >> 10, o = id & 1023;
    if (threadIdx.x < 64) s_h[threadIdx.x] = lrelu(h[b * 64 + threadIdx.x]);
    __syncthreads();
    float acc = 0.f;
    for (int k = 0; k < 64; ++k) acc += s_h[k] * w[k * 1024 + o];
    t1[b * 1024 + o] = lrelu(acc + bias[o]);
}

__global__ __launch_bounds__(256) void head_c_kernel(
    const float* __restrict__ h, const float* __restrict__ t1,
    const float* __restrict__ sw, const float* __restrict__ sb,
    const float* __restrict__ w2, const float* __restrict__ b2,
    float* __restrict__ h1)
{
    __shared__ float s_t[8 * 128];
    __shared__ float s_h[8 * 64];
    int oblk = blockIdx.x & 1, chunk = blockIdx.x >> 1;
    int t = threadIdx.x;
    int o = oblk * 256 + t;
    for (int j = t; j < 1024; j += 256) {
        int b = j >> 7, kk = j & 127;
        s_t[j] = t1[b * 1024 + chunk * 128 + kk];
    }
    if (chunk == 0)
        for (int j = t; j < 512; j += 256) s_h[j] = h[j];
    __syncthreads();
    float acc[8];
#pragma unroll
    for (int b = 0; b < 8; ++b) acc[b] = 0.f;
    for (int kk = 0; kk < 128; ++kk) {
        float wv = w2[(chunk * 128 + kk) * 512 + o];
#pragma unroll
        for (int b = 0; b < 8; ++b) acc[b] += s_t[b * 128 + kk] * wv;
    }
#pragma unroll
    for (int b = 0; b < 8; ++b) acc[b] *= 0.1f;
    if (chunk == 0) {
        for (int k = 0; k < 64; ++k) {
            float wv = sw[k * 512 + o];
#pragma unroll
            for (int b = 0; b < 8; ++b) acc[b] += s_h[b * 64 + k] * wv;
        }
        float c0 = sb[o] + 0.1f * b2[o];
#pragma unroll
        for (int b = 0; b < 8; ++b) acc[b] += c0;
    }
#pragma unroll
    for (int b = 0; b < 8; ++b) atomicAdd(&h1[b * 512 + o], acc[b]);
}

__global__ __launch_bounds__(256) void head_d_kernel(
    const float* __restrict__ h1, const float* __restrict__ w,
    const float* __restrict__ bias, float* __restrict__ z3)
{
    __shared__ float s_u[8 * 64];
    int oblk = blockIdx.x & 1, chunk = blockIdx.x >> 1;
    int t = threadIdx.x;
    int o = oblk * 256 + t;
    for (int j = t; j < 512; j += 256) {
        int b = j >> 6, kk = j & 63;
        s_u[j] = lrelu(h1[b * 512 + chunk * 64 + kk]);
    }
    __syncthreads();
    float acc[8];
#pragma unroll
    for (int b = 0; b < 8; ++b) acc[b] = 0.f;
    for (int kk = 0; kk < 64; ++kk) {
        float wv = w[(chunk * 64 + kk) * 512 + o];
#pragma unroll
        for (int b = 0; b < 8; ++b) acc[b] += s_u[b * 64 + kk] * wv;
    }
    if (chunk == 0) {
        float c0 = bias[o];
#pragma unroll
        for (int b = 0; b < 8; ++b) acc[b] += c0;
    }
#pragma unroll
    for (int b = 0; b < 8; ++b) atomicAdd(&z3[b * 512 + o], acc[b]);
}

__global__ __launch_bounds__(256) void head_e_kernel(
    const float* __restrict__ h1, const float* __restrict__ z3,
    const float* __restrict__ w, const float* __restrict__ bias,
    float* __restrict__ h2)
{
    __shared__ float s_u[8 * 64];
    int oblk = blockIdx.x & 1, chunk = blockIdx.x >> 1;
    int t = threadIdx.x;
    int o = oblk * 256 + t;
    for (int j = t; j < 512; j += 256) {
        int b = j >> 6, kk = j & 63;
        s_u[j] = lrelu(z3[b * 512 + chunk * 64 + kk]);
    }
    __syncthreads();
    float acc[8];
#pragma unroll
    for (int b = 0; b < 8; ++b) acc[b] = 0.f;
    for (int kk = 0; kk < 64; ++kk) {
        float wv = w[(chunk * 64 + kk) * 512 + o];
#pragma unroll
        for (int b = 0; b < 8; ++b) acc[b] += s_u[b * 64 + kk] * wv;
    }
#pragma unroll
    for (int b = 0; b < 8; ++b) acc[b] *= 0.1f;
    if (chunk == 0) {
        float c0 = 0.1f * bias[o];
#pragma unroll
        for (int b = 0; b < 8; ++b) acc[b] += h1[b * 512 + o] + c0;
    }
#pragma unroll
    for (int b = 0; b < 8; ++b) atomicAdd(&h2[b * 512 + o], acc[b]);
}

__global__ __launch_bounds__(256) void head_f_kernel(
    const float* __restrict__ h2, const float* __restrict__ w,
    const float* __restrict__ bias, float* __restrict__ lat)
{
    __shared__ float s_u[8 * 64];
    int oblk = blockIdx.x & 1, chunk = blockIdx.x >> 1;
    int t = threadIdx.x;
    int o = oblk * 256 + t;
    for (int j = t; j < 512; j += 256) {
        int b = j >> 6, kk = j & 63;
        s_u[j] = h2[b * 512 + chunk * 64 + kk];
    }
    __syncthreads();
    float acc[8];
#pragma unroll
    for (int b = 0; b < 8; ++b) acc[b] = 0.f;
    for (int kk = 0; kk < 64; ++kk) {
        float wv = w[(chunk * 64 + kk) * 512 + o];
#pragma unroll
        for (int b = 0; b < 8; ++b) acc[b] += s_u[b * 64 + kk] * wv;
    }
    if (chunk == 0) {
        float c0 = bias[o];
#pragma unroll
        for (int b = 0; b < 8; ++b) acc[b] += c0;
    }
#pragma unroll
    for (int b = 0; b < 8; ++b) atomicAdd(&lat[b * 512 + o], acc[b]);
}

// ---------------------------------------------------------------------------
extern "C" void kernel_launch(void* const* d_in, const int* in_sizes, int n_in,
                              void* d_out, int out_size, void* d_ws, size_t ws_size,
                              hipStream_t stream) {
    const float* x      = (const float*)d_in[0];
    const float* inj    = (const float*)d_in[1];
    const float* leak   = (const float*)d_in[2];
    const float* in_w   = (const float*)d_in[3];
    const float* in_b   = (const float*)d_in[4];
    const float* inrb_w0 = (const float*)d_in[5];
    const float* inrb_b0 = (const float*)d_in[6];
    const float* inrb_w1 = (const float*)d_in[7];
    const float* inrb_b1 = (const float*)d_in[8];
    const float* hyp_w  = (const float*)d_in[9];
    const float* hyp_b  = (const float*)d_in[10];
    const float* outrb_w0 = (const float*)d_in[11];
    const float* outrb_b0 = (const float*)d_in[12];
    const float* outrb_w1 = (const float*)d_in[13];
    const float* outrb_b1 = (const float*)d_in[14];
    const float* l1_sw  = (const float*)d_in[15];
    const float* l1_sb  = (const float*)d_in[16];
    const float* l1_w1  = (const float*)d_in[17];
    const float* l1_b1  = (const float*)d_in[18];
    const float* l1_w2  = (const float*)d_in[19];
    const float* l1_b2  = (const float*)d_in[20];
    const float* l2_w1  = (const float*)d_in[21];
    const float* l2_b1  = (const float*)d_in[22];
    const float* l2_w2  = (const float*)d_in[23];
    const float* l2_b2  = (const float*)d_in[24];
    const float* lo_w   = (const float*)d_in[25];
    const float* lo_b   = (const float*)d_in[26];

    float* out = (float*)d_out;
    float* dyn = (float*)d_ws;
    float* ybuf = dyn + (size_t)BATCH * PT;
    short* dyn16 = (short*)(ybuf + (size_t)BATCH * 64 * 16384);
    float* hbuf = (float*)(dyn16 + (size_t)BATCH * PT);
    float* t1buf = hbuf + 512;
    float* h1buf = t1buf + 8192;
    float* z3buf = h1buf + 4096;
    float* h2buf = z3buf + 4096;

    hipMemsetAsync(h1buf, 0, (4096 * 3) * sizeof(float), stream);
    hipMemsetAsync(out, 0, 4096 * sizeof(float), stream);

    hyper_kernel<<<(PT + 255) / 256, 256, 0, stream>>>(inj, hyp_w, hyp_b, dyn, dyn16);

    size_t cur = 4096;
    stem_kernel<<<BATCH * 256, 256, 0, stream>>>(
        x, in_w, in_b, inrb_w0, inrb_b0, inrb_w1, inrb_b1, out + cur);

    int S = 128, sh = 7;
    for (int i = 0; i < 6; ++i) {
        if (S >= 64) {
            iter_kernel<4><<<BATCH * (S * S / 64), 256, 0, stream>>>(
                out + cur, dyn, dyn16, leak, ybuf, S, sh);
        } else {
            iter_kernel<1><<<BATCH * (S * S / 16), 256, 0, stream>>>(
                out + cur, dyn, dyn16, leak, ybuf, S, sh);
        }
        int S2 = S >> 1;
        int total = BATCH * 64 * S2 * S2;
        size_t nxt = cur + (size_t)BATCH * 64 * S * S;
        down_kernel<<<(total + 255) / 256, 256, 0, stream>>>(ybuf, out + nxt, S, total);
        cur = nxt;
        S = S2; sh -= 1;
    }

    head_a_kernel<<<BATCH, 256, 0, stream>>>(
        out + cur, outrb_w0, outrb_b0, outrb_w1, outrb_b1, hbuf);
    head_b_kernel<<<32, 256, 0, stream>>>(hbuf, l1_w1, l1_b1, t1buf);
    head_c_kernel<<<16, 256, 0, stream>>>(hbuf, t1buf, l1_sw, l1_sb, l1_w2, l1_b2, h1buf);
    head_d_kernel<<<16, 256, 0, stream>>>(h1buf, l2_w1, l2_b1, z3buf);
    head_e_kernel<<<16, 256, 0, stream>>>(h1buf, z3buf, l2_w2, l2_b2, h2buf);
    head_f_kernel<<<16, 256, 0, stream>>>(h2buf, lo_w, lo_b, out);
}